// Round 6
// baseline (372.396 us; speedup 1.0000x reference)
//
#include <hip/hip_runtime.h>
#include <hip/hip_bf16.h>

// Problem constants
constexpr int N_ = 50000;
constexpr int D_ = 128;
constexpr int E_ = 800000;
constexpr int P_ = 9;
constexpr int L_ = 3;
constexpr float EPS_ = 1e-5f;

constexpr int TM = 128;   // rows per GEMM block (8 waves x 16 rows)
constexpr int CHUNK = 4096;                    // edges per hist/scatter block
constexpr int NBK = (E_ + CHUNK - 1) / CHUNK;  // 196 edge chunks
constexpr int NBUK = 196;                      // node buckets (50000>>8 = 195 max)
constexpr int HHALF = 256 * NBK;               // 50176 (per-half hist size)
constexpr int HTOT = 2 * HHALF;                // 100352 = 98 * 1024 exactly
constexpr int NSB = HTOT / 1024;               // 98 scan blocks
constexpr int MAT = L_ * P_;                   // 27 small matrices

typedef short bf16x8 __attribute__((ext_vector_type(8)));
typedef float f32x4 __attribute__((ext_vector_type(4)));

// async 16B global->LDS copy; lds base must be wave-uniform, data lands at
// base + lane*16  [guide §5, m97]
#define GLD16(gp, lp)                                                        \
    __builtin_amdgcn_global_load_lds(                                        \
        (const __attribute__((address_space(1))) unsigned int*)(gp),         \
        (__attribute__((address_space(3))) unsigned int*)(lp), 16, 0, 0)

__device__ inline unsigned short f2bf(float f) {
    __hip_bfloat16 h = __float2bfloat16(f);
    return *reinterpret_cast<unsigned short*>(&h);
}
__device__ inline float bflo(unsigned u) { return __uint_as_float(u << 16); }
__device__ inline float bfhi(unsigned u) { return __uint_as_float(u & 0xffff0000u); }
__device__ inline float bf2f(unsigned short h) {
    return __uint_as_float((unsigned)h << 16);
}
__device__ inline unsigned pack2bf(float a, float b) {
    return (unsigned)f2bf(a) | ((unsigned)f2bf(b) << 16);
}

// ---------------------------------------------------------------------------
// setup_nk: node polarity init + edge histograms (merged)
// ---------------------------------------------------------------------------

__global__ __launch_bounds__(256) void setup_nk(const int* __restrict__ ring,
                                                int* __restrict__ pol,
                                                int* __restrict__ bcnt,
                                                const int* __restrict__ ei,
                                                int* __restrict__ histG) {
    __shared__ int h[P_];
    __shared__ int hT[256], hS[256];
    int blk = blockIdx.x, tid = threadIdx.x;
    if (tid < P_) h[tid] = 0;
    hT[tid] = 0;
    hS[tid] = 0;
    __syncthreads();
    int n = blk * 256 + tid;
    if (n < N_) {
        int p = ring[n] % P_;
        pol[n] = p;
        atomicAdd(&h[p], 1);
    }
    int base = blk * CHUNK;
#pragma unroll
    for (int i = 0; i < CHUNK / 256; ++i) {
        int e = base + tid + i * 256;
        if (e < E_) {
            atomicAdd(&hS[ei[e] >> 8], 1);
            atomicAdd(&hT[ei[E_ + e] >> 8], 1);
        }
    }
    __syncthreads();
    if (tid < P_ && h[tid] > 0) atomicAdd(&bcnt[tid], h[tid]);
    histG[tid * NBK + blk] = hT[tid];
    histG[HHALF + tid * NBK + blk] = hS[tid];
}

// ---------------------------------------------------------------------------
// 3-phase exclusive scan of histG[HTOT]
// ---------------------------------------------------------------------------

__global__ __launch_bounds__(1024) void scanH1(int* __restrict__ a,
                                               int* __restrict__ blkSum) {
    __shared__ int wsum[16];
    int tid = threadIdx.x, lane = tid & 63, wid = tid >> 6;
    int idx = blockIdx.x * 1024 + tid;
    int v = a[idx];
    int inc = v;
#pragma unroll
    for (int o = 1; o < 64; o <<= 1) {
        int t = __shfl_up(inc, o, 64);
        if (lane >= o) inc += t;
    }
    if (lane == 63) wsum[wid] = inc;
    __syncthreads();
    if (tid < 16) {
        int s = wsum[tid];
#pragma unroll
        for (int o = 1; o < 16; o <<= 1) {
            int t = __shfl_up(s, o, 64);
            if (tid >= o) s += t;
        }
        wsum[tid] = s;
    }
    __syncthreads();
    int wexcl = (wid == 0) ? 0 : wsum[wid - 1];
    a[idx] = wexcl + inc - v;
    if (tid == 1023) blkSum[blockIdx.x] = wsum[15];
}

__global__ void scanH2(const int* __restrict__ blkSum, int* __restrict__ blkOff,
                       int* __restrict__ offT, const int* __restrict__ bcnt,
                       int* __restrict__ boff, int* __restrict__ tileOff) {
    if (threadIdx.x != 0) return;
    int run = 0;
    for (int i = 0; i < NSB; ++i) {
        blkOff[i] = run;
        run += blkSum[i];
    }
    offT[N_] = E_;
    boff[0] = 0;
    tileOff[0] = 0;
    for (int p = 0; p < P_; ++p) {
        boff[p + 1] = boff[p] + bcnt[p];
        tileOff[p + 1] = tileOff[p] + (bcnt[p] + TM - 1) / TM;
    }
}

__global__ __launch_bounds__(1024) void scanH3(int* __restrict__ a,
                                               const int* __restrict__ blkOff) {
    int idx = blockIdx.x * 1024 + threadIdx.x;
    a[idx] += blkOff[blockIdx.x];
}

// ---------------------------------------------------------------------------
// scatterTS: edge scatter (blocks [0,NBK)) | bucket_fill -> blist+perm
// (blocks [NBK, NBK+NBUK)). bucket_fill moved here so perm is ready before
// finalize3 writes eSrc/dnormp in PERMUTED (bucket-position) space.
// ---------------------------------------------------------------------------

__global__ __launch_bounds__(256) void scatterTS(const int* __restrict__ ei,
                                                 const int* __restrict__ histG,
                                                 unsigned* __restrict__ bufT,
                                                 unsigned char* __restrict__ bufS8,
                                                 const int* __restrict__ pol,
                                                 const int* __restrict__ boff,
                                                 int* __restrict__ bcur,
                                                 int* __restrict__ blist,
                                                 int* __restrict__ perm) {
    __shared__ int s0[256], s1[256];
    int blk = blockIdx.x, tid = threadIdx.x;
    if (blk < NBK) {
        s0[tid] = histG[tid * NBK + blk];
        s1[tid] = histG[HHALF + tid * NBK + blk] - E_;
        __syncthreads();
        int base = blk * CHUNK;
#pragma unroll
        for (int i = 0; i < CHUNK / 256; ++i) {
            int e = base + tid + i * 256;
            if (e < E_) {
                int s = ei[e], t = ei[E_ + e];
                int pT = atomicAdd(&s0[t >> 8], 1);
                bufT[pT] = ((unsigned)t << 16) | (unsigned)s;
                int pS = atomicAdd(&s1[s >> 8], 1);
                bufS8[pS] = (unsigned char)(s & 255);
            }
        }
    } else {
        int b = blk - NBK;
        if (tid < P_) s0[tid] = 0;
        __syncthreads();
        int n = b * 256 + tid;
        int p = 0, loc = 0;
        bool act = (n < N_);
        if (act) {
            p = pol[n];
            loc = atomicAdd(&s0[p], 1);
        }
        __syncthreads();
        if (tid < P_ && s0[tid] > 0) s1[tid] = atomicAdd(&bcur[tid], s0[tid]);
        __syncthreads();
        if (act) {
            int pos = boff[p] + s1[p] + loc;
            blist[pos] = n;
            perm[n] = pos;
        }
    }
}

// ---------------------------------------------------------------------------
// finalize3: finalizeT (eSrc in PERM space) | finalizeS (dnormp in PERM space)
// ---------------------------------------------------------------------------

__global__ __launch_bounds__(256) void finalize3(
    const unsigned* __restrict__ bufT, const unsigned char* __restrict__ bufS8,
    const int* __restrict__ histG, int* __restrict__ offT,
    unsigned short* __restrict__ eSrc, float* __restrict__ dnormp,
    const int* __restrict__ perm) {
    __shared__ int s0[256];
    __shared__ int s1[256];
    int bb = blockIdx.x, tid = threadIdx.x;

    if (bb < NBUK) {
        int b = bb;
        int start = histG[b * NBK];
        int end = histG[(b + 1) * NBK];
        s0[tid] = 0;
        __syncthreads();
        for (int i = start + tid; i < end; i += 256)
            atomicAdd(&s0[(bufT[i] >> 16) & 255], 1);
        __syncthreads();
        if (tid < 64) {
            int b0 = 4 * tid;
            int v0 = s0[b0], v1 = s0[b0 + 1], v2 = s0[b0 + 2], v3 = s0[b0 + 3];
            int lsum = v0 + v1 + v2 + v3;
            int inc = lsum;
#pragma unroll
            for (int o = 1; o < 64; o <<= 1) {
                int t = __shfl_up(inc, o, 64);
                if (tid >= o) inc += t;
            }
            int excl = inc - lsum;
            s1[b0] = excl;
            s1[b0 + 1] = excl + v0;
            s1[b0 + 2] = excl + v0 + v1;
            s1[b0 + 3] = excl + v0 + v1 + v2;
        }
        __syncthreads();
        int node = (b << 8) + tid;
        if (node < N_) offT[node] = start + s1[tid];
        __syncthreads();
        for (int i = start + tid; i < end; i += 256) {
            unsigned pk = bufT[i];
            int pos = start + atomicAdd(&s1[(pk >> 16) & 255], 1);
            eSrc[pos] = (unsigned short)perm[pk & 0xFFFF];  // position of src
        }
    } else {
        int b = bb - NBUK;
        int start = histG[HHALF + b * NBK] - E_;
        int end = histG[HHALF + (b + 1) * NBK] - E_;
        s0[tid] = 0;
        __syncthreads();
        for (int i = start + tid; i < end; i += 256) atomicAdd(&s0[bufS8[i]], 1);
        __syncthreads();
        int node = (b << 8) + tid;
        if (node < N_) {
            int dg = s0[tid];
            dnormp[perm[node]] = 1.f / (float)(dg > 1 ? dg : 1);
        }
    }
}

// ---------------------------------------------------------------------------
// prep_all: conv4 (PERMUTED xb + fp32 x0p) | zero rows | prep_S | prep_W2 |
// prep_split merged
// ---------------------------------------------------------------------------

constexpr int GCONV = N_ * D_ / 4 / 256;       // 6250
constexpr int GS = L_ * P_ * D_ * D_ / 256;    // 1728
constexpr int GW2 = L_ * D_ * D_ / 256;        // 192
constexpr int GSPL = (MAT + 6) * 16384 / 256;  // 2112
constexpr int GPREP = GCONV + 1 + GS + GW2 + GSPL;

__global__ __launch_bounds__(256) void prep_all(
    const float* __restrict__ x, unsigned short* __restrict__ xb,
    float* __restrict__ x0p, const int* __restrict__ perm,
    unsigned short* __restrict__ bufAb, unsigned short* __restrict__ bufBb,
    const float* __restrict__ S, const float* __restrict__ dS,
    unsigned short* __restrict__ Sb,
    const float* __restrict__ W2, unsigned short* __restrict__ W2b,
    const float* __restrict__ R, const float* __restrict__ dR,
    const float* __restrict__ W1, const float* __restrict__ Wr,
    unsigned short* __restrict__ Arh, unsigned short* __restrict__ Arl,
    unsigned short* __restrict__ W1h, unsigned short* __restrict__ W1l,
    unsigned short* __restrict__ Wrth, unsigned short* __restrict__ Wrtl) {
    int b = blockIdx.x, tid = threadIdx.x;
    if (b < GCONV) {
        int i = b * 256 + tid;
        int row = i >> 5, c = i & 31;  // 32 float4 per 128-col row
        int p = perm[row];
        float4 v = ((const float4*)x)[i];
        ushort4 o;
        o.x = f2bf(v.x); o.y = f2bf(v.y); o.z = f2bf(v.z); o.w = f2bf(v.w);
        ((ushort4*)xb)[(size_t)p * 32 + c] = o;
        ((float4*)x0p)[(size_t)p * 32 + c] = v;
    } else if (b < GCONV + 1) {
        if (tid < 64) {
            ((unsigned*)(xb + (size_t)N_ * D_))[tid] = 0;
            ((unsigned*)(bufAb + (size_t)N_ * D_))[tid] = 0;
            ((unsigned*)(bufBb + (size_t)N_ * D_))[tid] = 0;
        }
    } else if (b < GCONV + 1 + GS) {
        int idx = (b - GCONV - 1) * 256 + tid;
        int base = idx / (D_ * D_);
        int rem = idx % (D_ * D_);
        int c = rem / D_, d = rem % D_;
        size_t in = (size_t)base * D_ * D_ + (size_t)d * D_ + c;
        Sb[idx] = f2bf(S[in] + dS[in]);
    } else if (b < GCONV + 1 + GS + GW2) {
        int idx = (b - GCONV - 1 - GS) * 256 + tid;
        W2b[idx] = f2bf(W2[idx]);
    } else {
        constexpr int SZ1 = MAT * 16384;
        constexpr int SZ2 = SZ1 + 3 * 16384;
        int idx = (b - GCONV - 1 - GS - GW2) * 256 + tid;
        float v;
        unsigned short* oh;
        unsigned short* ol;
        int j;
        if (idx < SZ1) {
            v = R[idx] + dR[idx];
            oh = Arh; ol = Arl; j = idx;
        } else if (idx < SZ2) {
            j = idx - SZ1;
            v = W1[j];
            oh = W1h; ol = W1l;
        } else {
            j = idx - SZ2;
            int l = j >> 14, rem = j & 16383;
            int d = rem >> 7, i = rem & 127;
            v = Wr[(l << 14) + i * 128 + d];
            oh = Wrth; ol = Wrtl;
        }
        unsigned short h = f2bf(v);
        oh[j] = h;
        ol[j] = f2bf(v - bf2f(h));
    }
}

// ---------------------------------------------------------------------------
// Batched small MFMA GEMM (fp32-equivalent via 2-term bf16 split)
// ---------------------------------------------------------------------------

template <bool APM, bool BPM, bool OUT_SPLIT>
__global__ __launch_bounds__(256) void small_mfma(
    const unsigned short* __restrict__ Ah, const unsigned short* __restrict__ Al,
    const unsigned short* __restrict__ Bh, const unsigned short* __restrict__ Bl,
    unsigned short* __restrict__ Oh, unsigned short* __restrict__ Ol) {
    __shared__ unsigned short stg[(OUT_SPLIT ? 2 : 1) * 64 * 136];
    int tid = threadIdx.x, b = blockIdx.x;
    int mat = b >> 1, rb = b & 1;
    int l = mat / P_;
    size_t aoff = (size_t)(APM ? mat : l) * 16384 + (size_t)rb * 8192;
    size_t boff = (size_t)(BPM ? mat : l) * 16384;
    const unsigned short* ahp = Ah + aoff;
    const unsigned short* alp = Al + aoff;
    const unsigned short* bhp = Bh + boff;
    const unsigned short* blp = Bl + boff;

    int lane = tid & 63, wave = tid >> 6;
    int n = lane & 15, q = lane >> 4;
    int wr = wave * 16;

    f32x4 acc[8];
#pragma unroll
    for (int t = 0; t < 8; ++t) acc[t] = (f32x4){0.f, 0.f, 0.f, 0.f};

    int arow = (wr + n) * 128;
#pragma unroll
    for (int kc = 0; kc < 4; ++kc) {
        int ko = kc * 32 + q * 8;
        bf16x8 avh = *(const bf16x8*)(ahp + arow + ko);
        bf16x8 avl = *(const bf16x8*)(alp + arow + ko);
#pragma unroll
        for (int t = 0; t < 8; ++t) {
            int brow = (t * 16 + n) * 128;
            bf16x8 bvh = *(const bf16x8*)(bhp + brow + ko);
            bf16x8 bvl = *(const bf16x8*)(blp + brow + ko);
            acc[t] = __builtin_amdgcn_mfma_f32_16x16x32_bf16(avh, bvh, acc[t], 0, 0, 0);
            acc[t] = __builtin_amdgcn_mfma_f32_16x16x32_bf16(avh, bvl, acc[t], 0, 0, 0);
            acc[t] = __builtin_amdgcn_mfma_f32_16x16x32_bf16(avl, bvh, acc[t], 0, 0, 0);
        }
    }
#pragma unroll
    for (int t = 0; t < 8; ++t)
#pragma unroll
        for (int r = 0; r < 4; ++r) {
            int row = wr + q * 4 + r;
            float v = acc[t][r];
            unsigned short h = f2bf(v);
            stg[row * 136 + t * 16 + n] = h;
            if constexpr (OUT_SPLIT)
                stg[64 * 136 + row * 136 + t * 16 + n] = f2bf(v - bf2f(h));
        }
    __syncthreads();
    size_t obase = (size_t)mat * 16384 + (size_t)rb * 8192;
#pragma unroll
    for (int i = 0; i < 4; ++i) {
        int c = tid + i * 256;
        int r = c >> 4, off = c & 15;
        *(uint4*)(Oh + obase + r * 128 + off * 8) =
            *(const uint4*)(stg + r * 136 + off * 8);
        if constexpr (OUT_SPLIT)
            *(uint4*)(Ol + obase + r * 128 + off * 8) =
                *(const uint4*)(stg + 64 * 136 + r * 136 + off * 8);
    }
}

// ---------------------------------------------------------------------------
// CSR aggregation: gathers xt by POSITION (eSrc pre-permuted); output row
// scattered to perm[nd] (write-side scatter is fire-and-forget).
// ---------------------------------------------------------------------------

__device__ inline void accum_row(float* acc, uint4 r) {
    acc[0] += bflo(r.x); acc[1] += bfhi(r.x);
    acc[2] += bflo(r.y); acc[3] += bfhi(r.y);
    acc[4] += bflo(r.z); acc[5] += bfhi(r.z);
    acc[6] += bflo(r.w); acc[7] += bfhi(r.w);
}

__global__ __launch_bounds__(256) void aggregate_bf(const unsigned short* __restrict__ xt,
                                                    const int* __restrict__ offT,
                                                    const unsigned short* __restrict__ eSrc,
                                                    const int* __restrict__ perm,
                                                    unsigned short* __restrict__ agg) {
    int nd = blockIdx.x * 4 + (threadIdx.x >> 6);
    if (nd >= N_) return;
    int l = threadIdx.x & 63;
    int g = l >> 4, c16 = l & 15;
    int beg = offT[nd], end = offT[nd + 1];
    int pdst = perm[nd];

    float acc[8];
#pragma unroll
    for (int k = 0; k < 8; ++k) acc[k] = 0.f;

    for (int base = beg; base < end; base += 64) {
        int cnt = min(64, end - base);
        int idxv = (l < cnt) ? (int)eSrc[base + l] : 0;
        int steps = (cnt + 3) >> 2;
        int j = 0;
        for (; j + 3 < steps; j += 4) {
            int e0 = 4 * j + g, e1 = e0 + 4, e2 = e0 + 8, e3 = e0 + 12;
            int i0 = __shfl(idxv, e0, 64);
            int i1 = __shfl(idxv, e1, 64);
            int i2 = __shfl(idxv, e2, 64);
            int i3 = __shfl(idxv, e3, 64);
            int r0 = (e0 < cnt) ? i0 : N_;
            int r1 = (e1 < cnt) ? i1 : N_;
            int r2 = (e2 < cnt) ? i2 : N_;
            int r3 = (e3 < cnt) ? i3 : N_;
            uint4 v0 = ((const uint4*)(xt + (size_t)r0 * D_))[c16];
            uint4 v1 = ((const uint4*)(xt + (size_t)r1 * D_))[c16];
            uint4 v2 = ((const uint4*)(xt + (size_t)r2 * D_))[c16];
            uint4 v3 = ((const uint4*)(xt + (size_t)r3 * D_))[c16];
            accum_row(acc, v0);
            accum_row(acc, v1);
            accum_row(acc, v2);
            accum_row(acc, v3);
        }
        for (; j < steps; ++j) {
            int e0 = 4 * j + g;
            int i0 = __shfl(idxv, e0, 64);
            int r0 = (e0 < cnt) ? i0 : N_;
            uint4 v0 = ((const uint4*)(xt + (size_t)r0 * D_))[c16];
            accum_row(acc, v0);
        }
    }
#pragma unroll
    for (int k = 0; k < 8; ++k) {
        acc[k] += __shfl_xor(acc[k], 16, 64);
        acc[k] += __shfl_xor(acc[k], 32, 64);
    }
    if (g == 0) {
        uint4 o;
        o.x = (unsigned)f2bf(acc[0]) | ((unsigned)f2bf(acc[1]) << 16);
        o.y = (unsigned)f2bf(acc[2]) | ((unsigned)f2bf(acc[3]) << 16);
        o.z = (unsigned)f2bf(acc[4]) | ((unsigned)f2bf(acc[5]) << 16);
        o.w = (unsigned)f2bf(acc[6]) | ((unsigned)f2bf(acc[7]) << 16);
        ((uint4*)(agg + (size_t)pdst * D_))[c16] = o;
    }
}

// ---------------------------------------------------------------------------
// Swapped-GEMM, round 6: BUCKET-POSITION layout. All per-node intermediates
// (xt=bufAb, agg=bufBb, x'=xbuf, x0p, dnormp) are stored by bucket position,
// so each tile's rows are CONTIGUOUS: bg/xres/dn reads and OutF/OutXt writes
// are streams, not gathers (R5 lesson: wave count fixed at 3136 => TLP capped
// at ~12 waves/CU, so scattered-row latency was the residual bottleneck).
// Remaining scatters: prep's one-time x permute, aggregate's output write
// (no read stall), LAST's final out[node] store.
// Rows rowbase+nrows..rowbase+TM-1 of a tile overlap the next bucket: loads
// may read them (garbage stays in its own MFMA column/lane), stores guarded
// by rr<nrows. Buffers padded by TM rows.
// ---------------------------------------------------------------------------

// stage one 128x128 bf16 matrix into sB, async, 8 waves x 4 segs
__device__ inline void stage_B_async(const unsigned short* __restrict__ B,
                                     unsigned short* sB, int wave, int lane) {
    int rsub = lane >> 4, cl = lane & 15;
#pragma unroll
    for (int j = 0; j < 4; ++j) {
        int seg = wave * 4 + j;
        int row = seg * 4 + rsub;
        GLD16(B + row * 128 + ((cl ^ (row & 15)) << 3), sB + seg * 512);
    }
}

// build bf16x8 B-frag (dims 32kc+8q .. +7 of own row) from packed bf16 pairs
// Pl/Ph (Pl[t] = dims {16t+4q+0,1}, Ph[t] = {+2,+3}) via 4-lane exchange.
#define XCH_FRAG(dst, Pl, Ph, kc)                                            \
    {                                                                        \
        unsigned a0 = __shfl(Pl[2 * (kc)], s0, 64);                          \
        unsigned b0 = __shfl(Pl[2 * (kc) + 1], s0, 64);                      \
        unsigned a1 = __shfl(Ph[2 * (kc)], s0, 64);                          \
        unsigned b1 = __shfl(Ph[2 * (kc) + 1], s0, 64);                      \
        unsigned a2 = __shfl(Pl[2 * (kc)], s1, 64);                          \
        unsigned b2 = __shfl(Pl[2 * (kc) + 1], s1, 64);                      \
        unsigned a3 = __shfl(Ph[2 * (kc)], s1, 64);                          \
        unsigned b3 = __shfl(Ph[2 * (kc) + 1], s1, 64);                      \
        union { unsigned u[4]; bf16x8 v; } fu;                               \
        fu.u[0] = hi ? b0 : a0;                                              \
        fu.u[1] = hi ? b1 : a1;                                              \
        fu.u[2] = hi ? b2 : a2;                                              \
        fu.u[3] = hi ? b3 : a3;                                              \
        dst = fu.v;                                                          \
    }

// ---------------------------------------------------------------------------
// gemm_xt0: xt = xb @ Sb[0][pol], positions contiguous. 1 barrier, no rid.
// ---------------------------------------------------------------------------

__global__ __launch_bounds__(512, 4) void gemm_xt0(
    const unsigned short* __restrict__ A, const unsigned short* __restrict__ Bw,
    unsigned short* __restrict__ OutB,
    const int* __restrict__ boff, const int* __restrict__ tileOff) {
    __shared__ unsigned short sB[128 * 128];
    int tid = threadIdx.x, b = blockIdx.x;
    if (b >= tileOff[P_]) return;
    int pp = 0;
    while (pp < P_ - 1 && b >= tileOff[pp + 1]) ++pp;
    int tb = b - tileOff[pp];
    int cnt = boff[pp + 1] - boff[pp];
    int nrows = min(TM, cnt - tb * TM);
    int rowbase = boff[pp] + tb * TM;

    int lane = tid & 63, wave = tid >> 6;
    int n = lane & 15, q = lane >> 4;
    int rr = wave * 16 + n;
    size_t posr = (size_t)(rowbase + rr);

    stage_B_async(Bw + (size_t)pp * (D_ * D_), sB, wave, lane);
    bf16x8 bg[4];
#pragma unroll
    for (int kc = 0; kc < 4; ++kc)
        bg[kc] = *(const bf16x8*)(A + posr * 128 + kc * 32 + q * 8);
    __syncthreads();  // drains stage + bg

    f32x4 acc[8];
#pragma unroll
    for (int t = 0; t < 8; ++t) acc[t] = (f32x4){0.f, 0.f, 0.f, 0.f};
#pragma unroll
    for (int kc = 0; kc < 4; ++kc) {
#pragma unroll
        for (int t = 0; t < 8; ++t) {
            int cs = ((((kc << 2) + q) ^ n) << 3);
            bf16x8 af = *(const bf16x8*)(sB + (t * 16 + n) * 128 + cs);
            acc[t] = __builtin_amdgcn_mfma_f32_16x16x32_bf16(af, bg[kc], acc[t], 0, 0, 0);
        }
    }
    if (rr < nrows) {
#pragma unroll
        for (int t = 0; t < 8; ++t) {
            uint2 o;
            o.x = pack2bf(acc[t][0], acc[t][1]);
            o.y = pack2bf(acc[t][2], acc[t][3]);
            *(uint2*)(OutB + posr * 128 + t * 16 + q * 4) = o;
        }
    }
}

// ---------------------------------------------------------------------------
// fused_layer (swapped, 8-wave, position layout): GEMM1+LN+relu ->
// GEMM2+res+LN -> [GEMM3 unless LAST]. All row traffic contiguous except
// LAST's final scattered out[node] store.
// ---------------------------------------------------------------------------

template <bool LAST>
__global__ __launch_bounds__(512, 4) void fused_layer(
    const unsigned short* __restrict__ agg, const unsigned short* __restrict__ DmAll,
    const unsigned short* __restrict__ W2b, const unsigned short* __restrict__ SnAll,
    const int* __restrict__ blist, const int* __restrict__ boff,
    const int* __restrict__ tileOff, const float* __restrict__ dnormp,
    const float* __restrict__ b1v, const float* __restrict__ g1v,
    const float* __restrict__ e1v, const float* __restrict__ b2v,
    const float* __restrict__ g2v, const float* __restrict__ e2v,
    const float* __restrict__ rs_ptr, const float* __restrict__ xresp,
    const float* __restrict__ x0p, float* __restrict__ OutF,
    unsigned short* __restrict__ OutXt) {
    __shared__ unsigned short sB[128 * 128];  // 32 KiB (Dm -> W2 -> Sn)

    int tid = threadIdx.x, b = blockIdx.x;
    if (b >= tileOff[P_]) return;
    int pp = 0;
    while (pp < P_ - 1 && b >= tileOff[pp + 1]) ++pp;
    int tb = b - tileOff[pp];
    int cnt = boff[pp + 1] - boff[pp];
    int nrows = min(TM, cnt - tb * TM);
    int rowbase = boff[pp] + tb * TM;

    int lane = tid & 63, wave = tid >> 6;
    int n = lane & 15, q = lane >> 4;
    int rr = wave * 16 + n;
    size_t posr = (size_t)(rowbase + rr);
    int s0 = n + ((q & 1) << 5), s1 = s0 + 16;  // exchange partners (q-group)
    bool hi = q >= 2;

    stage_B_async(DmAll + (size_t)pp * (D_ * D_), sB, wave, lane);
    bf16x8 bg[4];
#pragma unroll
    for (int kc = 0; kc < 4; ++kc)
        bg[kc] = *(const bf16x8*)(agg + posr * 128 + kc * 32 + q * 8);
    float dn = dnormp[posr];
    __syncthreads();  // #1: sB(Dm) + bg ready

    // ---- GEMM1: out1^T = Dm^T @ agg^T  (lane holds row posr, d=16t+4q+r) ----
    f32x4 acc[8];
#pragma unroll
    for (int t = 0; t < 8; ++t) acc[t] = (f32x4){0.f, 0.f, 0.f, 0.f};
#pragma unroll
    for (int kc = 0; kc < 4; ++kc) {
#pragma unroll
        for (int t = 0; t < 8; ++t) {
            int cs = ((((kc << 2) + q) ^ n) << 3);
            bf16x8 af = *(const bf16x8*)(sB + (t * 16 + n) * 128 + cs);
            acc[t] = __builtin_amdgcn_mfma_f32_16x16x32_bf16(af, bg[kc], acc[t], 0, 0, 0);
        }
    }

    // ---- LN1 + relu -> h (packed bf16 pairs Pl/Ph) ----
    unsigned Pl[8], Ph[8];
    {
        float rs1 = 0.f, rs2 = 0.f;
#pragma unroll
        for (int t = 0; t < 8; ++t) {
            float4 bb = *(const float4*)(b1v + t * 16 + q * 4);
#pragma unroll
            for (int r = 0; r < 4; ++r) {
                float v = dn * acc[t][r] + (&bb.x)[r];
                acc[t][r] = v;
                rs1 += v;
                rs2 += v * v;
            }
        }
        rs1 += __shfl_xor(rs1, 16, 64);
        rs1 += __shfl_xor(rs1, 32, 64);
        rs2 += __shfl_xor(rs2, 16, 64);
        rs2 += __shfl_xor(rs2, 32, 64);
        float mm = rs1 * (1.f / 128.f);
        float rv = rsqrtf(rs2 * (1.f / 128.f) - mm * mm + EPS_);
#pragma unroll
        for (int t = 0; t < 8; ++t) {
            float4 gg = *(const float4*)(g1v + t * 16 + q * 4);
            float4 ee = *(const float4*)(e1v + t * 16 + q * 4);
            float h0 = fmaxf((acc[t][0] - mm) * rv * gg.x + ee.x, 0.f);
            float h1 = fmaxf((acc[t][1] - mm) * rv * gg.y + ee.y, 0.f);
            float h2 = fmaxf((acc[t][2] - mm) * rv * gg.z + ee.z, 0.f);
            float h3 = fmaxf((acc[t][3] - mm) * rv * gg.w + ee.w, 0.f);
            Pl[t] = pack2bf(h0, h1);
            Ph[t] = pack2bf(h2, h3);
        }
    }

    __syncthreads();                     // #2: sB(Dm) free
    stage_B_async(W2b, sB, wave, lane);  // async; overlapped by exchange
    bf16x8 h2[4];
#pragma unroll
    for (int kc = 0; kc < 4; ++kc) XCH_FRAG(h2[kc], Pl, Ph, kc)
    __syncthreads();  // #3: sB(W2) ready

    // ---- GEMM2: out2^T = W2 @ h^T ----
#pragma unroll
    for (int t = 0; t < 8; ++t) acc[t] = (f32x4){0.f, 0.f, 0.f, 0.f};
#pragma unroll
    for (int kc = 0; kc < 4; ++kc) {
#pragma unroll
        for (int t = 0; t < 8; ++t) {
            int cs = ((((kc << 2) + q) ^ n) << 3);
            bf16x8 af = *(const bf16x8*)(sB + (t * 16 + n) * 128 + cs);
            acc[t] = __builtin_amdgcn_mfma_f32_16x16x32_bf16(af, h2[kc], acc[t], 0, 0, 0);
        }
    }

    // ---- residual (CONTIGUOUS position read) + LN2 -> x' ----
    float rsc = rs_ptr[0];
    float4 xrq[8];
#pragma unroll
    for (int t = 0; t < 8; ++t)
        xrq[t] = *(const float4*)(xresp + posr * 128 + t * 16 + q * 4);
    {
        float rs1 = 0.f, rs2 = 0.f;
#pragma unroll
        for (int t = 0; t < 8; ++t) {
            float4 bb = *(const float4*)(b2v + t * 16 + q * 4);
#pragma unroll
            for (int r = 0; r < 4; ++r) {
                float v = rsc * (acc[t][r] + (&bb.x)[r]) + (&xrq[t].x)[r];
                acc[t][r] = v;
                rs1 += v;
                rs2 += v * v;
            }
        }
        rs1 += __shfl_xor(rs1, 16, 64);
        rs1 += __shfl_xor(rs1, 32, 64);
        rs2 += __shfl_xor(rs2, 16, 64);
        rs2 += __shfl_xor(rs2, 32, 64);
        float mm = rs1 * (1.f / 128.f);
        float rv = rsqrtf(rs2 * (1.f / 128.f) - mm * mm + EPS_);
        if constexpr (LAST) {
            int rw = (rr < nrows) ? blist[posr] : -1;
#pragma unroll
            for (int t = 0; t < 8; ++t) {
                float4 gg = *(const float4*)(g2v + t * 16 + q * 4);
                float4 ee = *(const float4*)(e2v + t * 16 + q * 4);
                float4 xa = *(const float4*)(x0p + posr * 128 + t * 16 + q * 4);
                if (rw >= 0) {
                    float4 o;
                    o.x = (acc[t][0] - mm) * rv * gg.x + ee.x + xa.x;
                    o.y = (acc[t][1] - mm) * rv * gg.y + ee.y + xa.y;
                    o.z = (acc[t][2] - mm) * rv * gg.z + ee.z + xa.z;
                    o.w = (acc[t][3] - mm) * rv * gg.w + ee.w + xa.w;
                    *(float4*)(OutF + (size_t)rw * 128 + t * 16 + q * 4) = o;
                }
            }
        } else {
#pragma unroll
            for (int t = 0; t < 8; ++t) {
                float4 gg = *(const float4*)(g2v + t * 16 + q * 4);
                float4 ee = *(const float4*)(e2v + t * 16 + q * 4);
                float4 o;
                o.x = (acc[t][0] - mm) * rv * gg.x + ee.x;
                o.y = (acc[t][1] - mm) * rv * gg.y + ee.y;
                o.z = (acc[t][2] - mm) * rv * gg.z + ee.z;
                o.w = (acc[t][3] - mm) * rv * gg.w + ee.w;
                xrq[t] = o;  // keep fp32 x' for deferred OutF store
                Pl[t] = pack2bf(o.x, o.y);
                Ph[t] = pack2bf(o.z, o.w);
            }
        }
    }

    if constexpr (!LAST) {
        __syncthreads();  // #4: sB(W2) free
        stage_B_async(SnAll + (size_t)pp * (D_ * D_), sB, wave, lane);
        bf16x8 x2[4];
#pragma unroll
        for (int kc = 0; kc < 4; ++kc) XCH_FRAG(x2[kc], Pl, Ph, kc)
        __syncthreads();  // #5: sB(Sn) ready

        // ---- GEMM3: xt^T = Sn^T @ x'^T ----
#pragma unroll
        for (int t = 0; t < 8; ++t) acc[t] = (f32x4){0.f, 0.f, 0.f, 0.f};
#pragma unroll
        for (int kc = 0; kc < 4; ++kc) {
#pragma unroll
            for (int t = 0; t < 8; ++t) {
                int cs = ((((kc << 2) + q) ^ n) << 3);
                bf16x8 af = *(const bf16x8*)(sB + (t * 16 + n) * 128 + cs);
                acc[t] = __builtin_amdgcn_mfma_f32_16x16x32_bf16(af, x2[kc], acc[t], 0, 0, 0);
            }
        }
        if (rr < nrows) {
#pragma unroll
            for (int t = 0; t < 8; ++t) {
                uint2 o;
                o.x = pack2bf(acc[t][0], acc[t][1]);
                o.y = pack2bf(acc[t][2], acc[t][3]);
                *(uint2*)(OutXt + posr * 128 + t * 16 + q * 4) = o;
            }
#pragma unroll
            for (int t = 0; t < 8; ++t)
                *(float4*)(OutF + posr * 128 + t * 16 + q * 4) = xrq[t];
        }
    }
}

// ---------------------------------------------------------------------------
// Host launch
// ---------------------------------------------------------------------------

extern "C" void kernel_launch(void* const* d_in, const int* in_sizes, int n_in,
                              void* d_out, int out_size, void* d_ws, size_t ws_size,
                              hipStream_t stream) {
    const float* x0 = (const float*)d_in[0];
    const int* ei = (const int*)d_in[1];
    const int* ring = (const int*)d_in[2];
    const float* Wr = (const float*)d_in[3];
    const float* S = (const float*)d_in[4];
    const float* dS = (const float*)d_in[5];
    const float* R = (const float*)d_in[6];
    const float* dR = (const float*)d_in[7];
    const float* rsc = (const float*)d_in[8];
    const float* W1 = (const float*)d_in[9];
    const float* b1 = (const float*)d_in[10];
    const float* lng = (const float*)d_in[11];
    const float* lnb = (const float*)d_in[12];
    const float* W2 = (const float*)d_in[13];
    const float* b2 = (const float*)d_in[14];
    const float* ng = (const float*)d_in[15];
    const float* nb = (const float*)d_in[16];
    float* out = (float*)d_out;

    char* w = (char*)d_ws;
    auto alloc = [&](size_t bytes) {
        char* p = w;
        w += (bytes + 15) & ~(size_t)15;
        return p;
    };
    const size_t NP = (size_t)N_ + TM + 1;  // padded row count (pos space)
    unsigned short* xb = (unsigned short*)alloc(NP * D_ * 2);     // bf16 x0, pos order (+pad)
    unsigned short* bufAb = (unsigned short*)alloc(NP * D_ * 2);  // xt, pos order (+zero row N)
    unsigned short* bufBb = (unsigned short*)alloc(NP * D_ * 2);  // agg, pos order (+zero row N)
    float* xbuf = (float*)alloc(NP * D_ * 4);                     // fp32 x', pos order
    float* x0p = (float*)alloc(NP * D_ * 4);                      // fp32 x0, pos order
    unsigned short* Sb = (unsigned short*)alloc((size_t)L_ * P_ * D_ * D_ * 2);
    unsigned short* Dmb = (unsigned short*)alloc((size_t)L_ * P_ * D_ * D_ * 2);
    unsigned short* W2b = (unsigned short*)alloc((size_t)L_ * D_ * D_ * 2);
    unsigned short* Arh = (unsigned short*)alloc((size_t)MAT * 16384 * 2);
    unsigned short* Arl = (unsigned short*)alloc((size_t)MAT * 16384 * 2);
    unsigned short* W1h = (unsigned short*)alloc((size_t)3 * 16384 * 2);
    unsigned short* W1l = (unsigned short*)alloc((size_t)3 * 16384 * 2);
    unsigned short* Wrth = (unsigned short*)alloc((size_t)3 * 16384 * 2);
    unsigned short* Wrtl = (unsigned short*)alloc((size_t)3 * 16384 * 2);
    unsigned short* T1th = (unsigned short*)alloc((size_t)MAT * 16384 * 2);
    unsigned short* T1tl = (unsigned short*)alloc((size_t)MAT * 16384 * 2);
    float* dnormp = (float*)alloc(NP * 4);  // pos order
    int* histG = (int*)alloc((size_t)HTOT * 4);
    unsigned* bufT = (unsigned*)alloc((size_t)E_ * 4);
    unsigned char* bufS8 = (unsigned char*)alloc((size_t)E_);
    unsigned short* eSrc = (unsigned short*)alloc((size_t)E_ * 2);
    int* offT = (int*)alloc((size_t)(N_ + 1) * 4);
    int* pol = (int*)alloc((size_t)N_ * 4);
    int* boff = (int*)alloc((size_t)(P_ + 1) * 4);
    int* tileOff = (int*)alloc((size_t)(P_ + 1) * 4);
    int* blist = (int*)alloc(NP * 4);
    int* perm = (int*)alloc((size_t)N_ * 4);
    int* blkSum = (int*)alloc((size_t)NSB * 4);
    int* blkOff = (int*)alloc((size_t)NSB * 4);
    int* bcnt = (int*)alloc((size_t)2 * P_ * 4);  // zeroed region: bcnt + bcur
    int* bcur = bcnt + P_;

    hipMemsetAsync(bcnt, 0, (size_t)2 * P_ * 4, stream);

    const int BTILES = N_ / TM + P_;  // 399, upper bound on bucketed tiles

    setup_nk<<<NBK, 256, 0, stream>>>(ring, pol, bcnt, ei, histG);
    scanH1<<<NSB, 1024, 0, stream>>>(histG, blkSum);
    scanH2<<<1, 64, 0, stream>>>(blkSum, blkOff, offT, bcnt, boff, tileOff);
    scanH3<<<NSB, 1024, 0, stream>>>(histG, blkOff);
    scatterTS<<<NBK + NBUK, 256, 0, stream>>>(ei, histG, bufT, bufS8,
                                              pol, boff, bcur, blist, perm);
    finalize3<<<2 * NBUK, 256, 0, stream>>>(bufT, bufS8, histG, offT, eSrc,
                                            dnormp, perm);
    prep_all<<<GPREP, 256, 0, stream>>>(x0, xb, x0p, perm, bufAb, bufBb,
                                        S, dS, Sb, W2, W2b,
                                        R, dR, W1, Wr, Arh, Arl, W1h, W1l, Wrth, Wrtl);
    // T1t[mat][k][i] = sum_j W1[l][k][j] * (R+dR)[mat][i][j]
    small_mfma<false, true, true><<<2 * MAT, 256, 0, stream>>>(
        W1h, W1l, Arh, Arl, T1th, T1tl);
    // Dmb[mat][k][d] = sum_i T1t[mat][k][i] * Wr^T[l][d][i]
    small_mfma<true, false, false><<<2 * MAT, 256, 0, stream>>>(
        T1th, T1tl, Wrth, Wrtl, Dmb, nullptr);

    // layer 0 send-transform: xt0 = x0 @ (S+dS)[0][pol], position space
    gemm_xt0<<<BTILES, 512, 0, stream>>>(xb, Sb, bufAb, boff, tileOff);

    for (int l = 0; l < L_; ++l) {
        const size_t lPDD = (size_t)l * P_ * D_ * D_;
        const size_t lDD = (size_t)l * D_ * D_;
        const size_t lD = (size_t)l * D_;
        aggregate_bf<<<N_ / 4, 256, 0, stream>>>(bufAb, offT, eSrc, perm, bufBb);
        const float* xrp = (l == 0) ? x0p : xbuf;
        if (l < L_ - 1) {
            fused_layer<false><<<BTILES, 512, 0, stream>>>(
                bufBb, Dmb + lPDD, W2b + lDD, Sb + lPDD + (size_t)P_ * D_ * D_,
                blist, boff, tileOff, dnormp,
                b1 + lD, lng + lD, lnb + lD, b2 + lD, ng + lD, nb + lD,
                rsc + l, xrp, nullptr, xbuf, bufAb);
        } else {
            fused_layer<true><<<BTILES, 512, 0, stream>>>(
                bufBb, Dmb + lPDD, W2b + lDD, nullptr,
                blist, boff, tileOff, dnormp,
                b1 + lD, lng + lD, lnb + lD, b2 + lD, ng + lD, nb + lD,
                rsc + l, xrp, x0p, out, nullptr);
        }
    }
}

// Round 7
// 367.675 us; speedup vs baseline: 1.0128x; 1.0128x over previous
//
#include <hip/hip_runtime.h>
#include <hip/hip_bf16.h>

// Problem constants
constexpr int N_ = 50000;
constexpr int D_ = 128;
constexpr int E_ = 800000;
constexpr int P_ = 9;
constexpr int L_ = 3;
constexpr float EPS_ = 1e-5f;

constexpr int TM = 128;   // rows per GEMM block (8 waves x 16 rows)
constexpr int CHUNK = 4096;                    // edges per hist/scatter block
constexpr int NBK = (E_ + CHUNK - 1) / CHUNK;  // 196 edge chunks
constexpr int NBUK = 196;                      // node buckets (50000>>8 = 195 max)
constexpr int HHALF = 256 * NBK;               // 50176 (per-half hist size)
constexpr int HTOT = 2 * HHALF;                // 100352 = 98 * 1024 exactly
constexpr int NSB = HTOT / 1024;               // 98 scan blocks
constexpr int MAT = L_ * P_;                   // 27 small matrices

typedef short bf16x8 __attribute__((ext_vector_type(8)));
typedef float f32x4 __attribute__((ext_vector_type(4)));

// async 16B global->LDS copy; lds base must be wave-uniform, data lands at
// base + lane*16  [guide §5, m97]
#define GLD16(gp, lp)                                                        \
    __builtin_amdgcn_global_load_lds(                                        \
        (const __attribute__((address_space(1))) unsigned int*)(gp),         \
        (__attribute__((address_space(3))) unsigned int*)(lp), 16, 0, 0)

__device__ inline unsigned short f2bf(float f) {
    __hip_bfloat16 h = __float2bfloat16(f);
    return *reinterpret_cast<unsigned short*>(&h);
}
__device__ inline float bflo(unsigned u) { return __uint_as_float(u << 16); }
__device__ inline float bfhi(unsigned u) { return __uint_as_float(u & 0xffff0000u); }
__device__ inline float bf2f(unsigned short h) {
    return __uint_as_float((unsigned)h << 16);
}
__device__ inline unsigned pack2bf(float a, float b) {
    return (unsigned)f2bf(a) | ((unsigned)f2bf(b) << 16);
}

// ---------------------------------------------------------------------------
// setup_nk: node polarity init + edge histograms (merged)
// ---------------------------------------------------------------------------

__global__ __launch_bounds__(256) void setup_nk(const int* __restrict__ ring,
                                                int* __restrict__ pol,
                                                int* __restrict__ bcnt,
                                                const int* __restrict__ ei,
                                                int* __restrict__ histG) {
    __shared__ int h[P_];
    __shared__ int hT[256], hS[256];
    int blk = blockIdx.x, tid = threadIdx.x;
    if (tid < P_) h[tid] = 0;
    hT[tid] = 0;
    hS[tid] = 0;
    __syncthreads();
    int n = blk * 256 + tid;
    if (n < N_) {
        int p = ring[n] % P_;
        pol[n] = p;
        atomicAdd(&h[p], 1);
    }
    int base = blk * CHUNK;
#pragma unroll
    for (int i = 0; i < CHUNK / 256; ++i) {
        int e = base + tid + i * 256;
        if (e < E_) {
            atomicAdd(&hS[ei[e] >> 8], 1);
            atomicAdd(&hT[ei[E_ + e] >> 8], 1);
        }
    }
    __syncthreads();
    if (tid < P_ && h[tid] > 0) atomicAdd(&bcnt[tid], h[tid]);
    histG[tid * NBK + blk] = hT[tid];
    histG[HHALF + tid * NBK + blk] = hS[tid];
}

// ---------------------------------------------------------------------------
// 3-phase exclusive scan of histG[HTOT]
// ---------------------------------------------------------------------------

__global__ __launch_bounds__(1024) void scanH1(int* __restrict__ a,
                                               int* __restrict__ blkSum) {
    __shared__ int wsum[16];
    int tid = threadIdx.x, lane = tid & 63, wid = tid >> 6;
    int idx = blockIdx.x * 1024 + tid;
    int v = a[idx];
    int inc = v;
#pragma unroll
    for (int o = 1; o < 64; o <<= 1) {
        int t = __shfl_up(inc, o, 64);
        if (lane >= o) inc += t;
    }
    if (lane == 63) wsum[wid] = inc;
    __syncthreads();
    if (tid < 16) {
        int s = wsum[tid];
#pragma unroll
        for (int o = 1; o < 16; o <<= 1) {
            int t = __shfl_up(s, o, 64);
            if (tid >= o) s += t;
        }
        wsum[tid] = s;
    }
    __syncthreads();
    int wexcl = (wid == 0) ? 0 : wsum[wid - 1];
    a[idx] = wexcl + inc - v;
    if (tid == 1023) blkSum[blockIdx.x] = wsum[15];
}

__global__ void scanH2(const int* __restrict__ blkSum, int* __restrict__ blkOff,
                       int* __restrict__ offT, const int* __restrict__ bcnt,
                       int* __restrict__ boff, int* __restrict__ tileOff) {
    if (threadIdx.x != 0) return;
    int run = 0;
    for (int i = 0; i < NSB; ++i) {
        blkOff[i] = run;
        run += blkSum[i];
    }
    offT[N_] = E_;
    boff[0] = 0;
    tileOff[0] = 0;
    for (int p = 0; p < P_; ++p) {
        boff[p + 1] = boff[p] + bcnt[p];
        tileOff[p + 1] = tileOff[p] + (bcnt[p] + TM - 1) / TM;
    }
}

__global__ __launch_bounds__(1024) void scanH3(int* __restrict__ a,
                                               const int* __restrict__ blkOff) {
    int idx = blockIdx.x * 1024 + threadIdx.x;
    a[idx] += blkOff[blockIdx.x];
}

// ---------------------------------------------------------------------------
// scatterTS: edge scatter (blocks [0,NBK)) | bucket_fill -> blist+perm
// (blocks [NBK, NBK+NBUK)). bucket_fill here so perm is ready before
// finalize3 writes eSrc/dnormp in PERMUTED (bucket-position) space.
// ---------------------------------------------------------------------------

__global__ __launch_bounds__(256) void scatterTS(const int* __restrict__ ei,
                                                 const int* __restrict__ histG,
                                                 unsigned* __restrict__ bufT,
                                                 unsigned char* __restrict__ bufS8,
                                                 const int* __restrict__ pol,
                                                 const int* __restrict__ boff,
                                                 int* __restrict__ bcur,
                                                 int* __restrict__ blist,
                                                 int* __restrict__ perm) {
    __shared__ int s0[256], s1[256];
    int blk = blockIdx.x, tid = threadIdx.x;
    if (blk < NBK) {
        s0[tid] = histG[tid * NBK + blk];
        s1[tid] = histG[HHALF + tid * NBK + blk] - E_;
        __syncthreads();
        int base = blk * CHUNK;
#pragma unroll
        for (int i = 0; i < CHUNK / 256; ++i) {
            int e = base + tid + i * 256;
            if (e < E_) {
                int s = ei[e], t = ei[E_ + e];
                int pT = atomicAdd(&s0[t >> 8], 1);
                bufT[pT] = ((unsigned)t << 16) | (unsigned)s;
                int pS = atomicAdd(&s1[s >> 8], 1);
                bufS8[pS] = (unsigned char)(s & 255);
            }
        }
    } else {
        int b = blk - NBK;
        if (tid < P_) s0[tid] = 0;
        __syncthreads();
        int n = b * 256 + tid;
        int p = 0, loc = 0;
        bool act = (n < N_);
        if (act) {
            p = pol[n];
            loc = atomicAdd(&s0[p], 1);
        }
        __syncthreads();
        if (tid < P_ && s0[tid] > 0) s1[tid] = atomicAdd(&bcur[tid], s0[tid]);
        __syncthreads();
        if (act) {
            int pos = boff[p] + s1[p] + loc;
            blist[pos] = n;
            perm[n] = pos;
        }
    }
}

// ---------------------------------------------------------------------------
// finalize3: finalizeT (eSrc in PERM space) | finalizeS (dnormp in PERM space)
// ---------------------------------------------------------------------------

__global__ __launch_bounds__(256) void finalize3(
    const unsigned* __restrict__ bufT, const unsigned char* __restrict__ bufS8,
    const int* __restrict__ histG, int* __restrict__ offT,
    unsigned short* __restrict__ eSrc, float* __restrict__ dnormp,
    const int* __restrict__ perm) {
    __shared__ int s0[256];
    __shared__ int s1[256];
    int bb = blockIdx.x, tid = threadIdx.x;

    if (bb < NBUK) {
        int b = bb;
        int start = histG[b * NBK];
        int end = histG[(b + 1) * NBK];
        s0[tid] = 0;
        __syncthreads();
        for (int i = start + tid; i < end; i += 256)
            atomicAdd(&s0[(bufT[i] >> 16) & 255], 1);
        __syncthreads();
        if (tid < 64) {
            int b0 = 4 * tid;
            int v0 = s0[b0], v1 = s0[b0 + 1], v2 = s0[b0 + 2], v3 = s0[b0 + 3];
            int lsum = v0 + v1 + v2 + v3;
            int inc = lsum;
#pragma unroll
            for (int o = 1; o < 64; o <<= 1) {
                int t = __shfl_up(inc, o, 64);
                if (tid >= o) inc += t;
            }
            int excl = inc - lsum;
            s1[b0] = excl;
            s1[b0 + 1] = excl + v0;
            s1[b0 + 2] = excl + v0 + v1;
            s1[b0 + 3] = excl + v0 + v1 + v2;
        }
        __syncthreads();
        int node = (b << 8) + tid;
        if (node < N_) offT[node] = start + s1[tid];
        __syncthreads();
        for (int i = start + tid; i < end; i += 256) {
            unsigned pk = bufT[i];
            int pos = start + atomicAdd(&s1[(pk >> 16) & 255], 1);
            eSrc[pos] = (unsigned short)perm[pk & 0xFFFF];  // position of src
        }
    } else {
        int b = bb - NBUK;
        int start = histG[HHALF + b * NBK] - E_;
        int end = histG[HHALF + (b + 1) * NBK] - E_;
        s0[tid] = 0;
        __syncthreads();
        for (int i = start + tid; i < end; i += 256) atomicAdd(&s0[bufS8[i]], 1);
        __syncthreads();
        int node = (b << 8) + tid;
        if (node < N_) {
            int dg = s0[tid];
            dnormp[perm[node]] = 1.f / (float)(dg > 1 ? dg : 1);
        }
    }
}

// ---------------------------------------------------------------------------
// prep_all: conv4 (PERMUTED xb, bf16 only — x0p fp32 copy DROPPED, R6 showed
// contiguity of the residual stream is worthless) | zero rows | prep_S |
// prep_W2 | prep_split merged
// ---------------------------------------------------------------------------

constexpr int GCONV = N_ * D_ / 4 / 256;       // 6250
constexpr int GS = L_ * P_ * D_ * D_ / 256;    // 1728
constexpr int GW2 = L_ * D_ * D_ / 256;        // 192
constexpr int GSPL = (MAT + 6) * 16384 / 256;  // 2112
constexpr int GPREP = GCONV + 1 + GS + GW2 + GSPL;

__global__ __launch_bounds__(256) void prep_all(
    const float* __restrict__ x, unsigned short* __restrict__ xb,
    const int* __restrict__ perm,
    unsigned short* __restrict__ bufAb, unsigned short* __restrict__ bufBb,
    const float* __restrict__ S, const float* __restrict__ dS,
    unsigned short* __restrict__ Sb,
    const float* __restrict__ W2, unsigned short* __restrict__ W2b,
    const float* __restrict__ R, const float* __restrict__ dR,
    const float* __restrict__ W1, const float* __restrict__ Wr,
    unsigned short* __restrict__ Arh, unsigned short* __restrict__ Arl,
    unsigned short* __restrict__ W1h, unsigned short* __restrict__ W1l,
    unsigned short* __restrict__ Wrth, unsigned short* __restrict__ Wrtl) {
    int b = blockIdx.x, tid = threadIdx.x;
    if (b < GCONV) {
        int i = b * 256 + tid;
        int row = i >> 5, c = i & 31;  // 32 float4 per 128-col row
        int p = perm[row];
        float4 v = ((const float4*)x)[i];
        ushort4 o;
        o.x = f2bf(v.x); o.y = f2bf(v.y); o.z = f2bf(v.z); o.w = f2bf(v.w);
        ((ushort4*)xb)[(size_t)p * 32 + c] = o;
    } else if (b < GCONV + 1) {
        if (tid < 64) {
            ((unsigned*)(xb + (size_t)N_ * D_))[tid] = 0;
            ((unsigned*)(bufAb + (size_t)N_ * D_))[tid] = 0;
            ((unsigned*)(bufBb + (size_t)N_ * D_))[tid] = 0;
        }
    } else if (b < GCONV + 1 + GS) {
        int idx = (b - GCONV - 1) * 256 + tid;
        int base = idx / (D_ * D_);
        int rem = idx % (D_ * D_);
        int c = rem / D_, d = rem % D_;
        size_t in = (size_t)base * D_ * D_ + (size_t)d * D_ + c;
        Sb[idx] = f2bf(S[in] + dS[in]);
    } else if (b < GCONV + 1 + GS + GW2) {
        int idx = (b - GCONV - 1 - GS) * 256 + tid;
        W2b[idx] = f2bf(W2[idx]);
    } else {
        constexpr int SZ1 = MAT * 16384;
        constexpr int SZ2 = SZ1 + 3 * 16384;
        int idx = (b - GCONV - 1 - GS - GW2) * 256 + tid;
        float v;
        unsigned short* oh;
        unsigned short* ol;
        int j;
        if (idx < SZ1) {
            v = R[idx] + dR[idx];
            oh = Arh; ol = Arl; j = idx;
        } else if (idx < SZ2) {
            j = idx - SZ1;
            v = W1[j];
            oh = W1h; ol = W1l;
        } else {
            j = idx - SZ2;
            int l = j >> 14, rem = j & 16383;
            int d = rem >> 7, i = rem & 127;
            v = Wr[(l << 14) + i * 128 + d];
            oh = Wrth; ol = Wrtl;
        }
        unsigned short h = f2bf(v);
        oh[j] = h;
        ol[j] = f2bf(v - bf2f(h));
    }
}

// ---------------------------------------------------------------------------
// Batched small MFMA GEMM (fp32-equivalent via 2-term bf16 split)
// ---------------------------------------------------------------------------

template <bool APM, bool BPM, bool OUT_SPLIT>
__global__ __launch_bounds__(256) void small_mfma(
    const unsigned short* __restrict__ Ah, const unsigned short* __restrict__ Al,
    const unsigned short* __restrict__ Bh, const unsigned short* __restrict__ Bl,
    unsigned short* __restrict__ Oh, unsigned short* __restrict__ Ol) {
    __shared__ unsigned short stg[(OUT_SPLIT ? 2 : 1) * 64 * 136];
    int tid = threadIdx.x, b = blockIdx.x;
    int mat = b >> 1, rb = b & 1;
    int l = mat / P_;
    size_t aoff = (size_t)(APM ? mat : l) * 16384 + (size_t)rb * 8192;
    size_t boff = (size_t)(BPM ? mat : l) * 16384;
    const unsigned short* ahp = Ah + aoff;
    const unsigned short* alp = Al + aoff;
    const unsigned short* bhp = Bh + boff;
    const unsigned short* blp = Bl + boff;

    int lane = tid & 63, wave = tid >> 6;
    int n = lane & 15, q = lane >> 4;
    int wr = wave * 16;

    f32x4 acc[8];
#pragma unroll
    for (int t = 0; t < 8; ++t) acc[t] = (f32x4){0.f, 0.f, 0.f, 0.f};

    int arow = (wr + n) * 128;
#pragma unroll
    for (int kc = 0; kc < 4; ++kc) {
        int ko = kc * 32 + q * 8;
        bf16x8 avh = *(const bf16x8*)(ahp + arow + ko);
        bf16x8 avl = *(const bf16x8*)(alp + arow + ko);
#pragma unroll
        for (int t = 0; t < 8; ++t) {
            int brow = (t * 16 + n) * 128;
            bf16x8 bvh = *(const bf16x8*)(bhp + brow + ko);
            bf16x8 bvl = *(const bf16x8*)(blp + brow + ko);
            acc[t] = __builtin_amdgcn_mfma_f32_16x16x32_bf16(avh, bvh, acc[t], 0, 0, 0);
            acc[t] = __builtin_amdgcn_mfma_f32_16x16x32_bf16(avh, bvl, acc[t], 0, 0, 0);
            acc[t] = __builtin_amdgcn_mfma_f32_16x16x32_bf16(avl, bvh, acc[t], 0, 0, 0);
        }
    }
#pragma unroll
    for (int t = 0; t < 8; ++t)
#pragma unroll
        for (int r = 0; r < 4; ++r) {
            int row = wr + q * 4 + r;
            float v = acc[t][r];
            unsigned short h = f2bf(v);
            stg[row * 136 + t * 16 + n] = h;
            if constexpr (OUT_SPLIT)
                stg[64 * 136 + row * 136 + t * 16 + n] = f2bf(v - bf2f(h));
        }
    __syncthreads();
    size_t obase = (size_t)mat * 16384 + (size_t)rb * 8192;
#pragma unroll
    for (int i = 0; i < 4; ++i) {
        int c = tid + i * 256;
        int r = c >> 4, off = c & 15;
        *(uint4*)(Oh + obase + r * 128 + off * 8) =
            *(const uint4*)(stg + r * 136 + off * 8);
        if constexpr (OUT_SPLIT)
            *(uint4*)(Ol + obase + r * 128 + off * 8) =
                *(const uint4*)(stg + 64 * 136 + r * 136 + off * 8);
    }
}

// ---------------------------------------------------------------------------
// CSR aggregation: gathers xt by POSITION (eSrc pre-permuted); output row
// scattered to perm[nd] (write-side scatter is fire-and-forget).
// ---------------------------------------------------------------------------

__device__ inline void accum_row(float* acc, uint4 r) {
    acc[0] += bflo(r.x); acc[1] += bfhi(r.x);
    acc[2] += bflo(r.y); acc[3] += bfhi(r.y);
    acc[4] += bflo(r.z); acc[5] += bfhi(r.z);
    acc[6] += bflo(r.w); acc[7] += bfhi(r.w);
}

__global__ __launch_bounds__(256) void aggregate_bf(const unsigned short* __restrict__ xt,
                                                    const int* __restrict__ offT,
                                                    const unsigned short* __restrict__ eSrc,
                                                    const int* __restrict__ perm,
                                                    unsigned short* __restrict__ agg) {
    int nd = blockIdx.x * 4 + (threadIdx.x >> 6);
    if (nd >= N_) return;
    int l = threadIdx.x & 63;
    int g = l >> 4, c16 = l & 15;
    int beg = offT[nd], end = offT[nd + 1];
    int pdst = perm[nd];

    float acc[8];
#pragma unroll
    for (int k = 0; k < 8; ++k) acc[k] = 0.f;

    for (int base = beg; base < end; base += 64) {
        int cnt = min(64, end - base);
        int idxv = (l < cnt) ? (int)eSrc[base + l] : 0;
        int steps = (cnt + 3) >> 2;
        int j = 0;
        for (; j + 3 < steps; j += 4) {
            int e0 = 4 * j + g, e1 = e0 + 4, e2 = e0 + 8, e3 = e0 + 12;
            int i0 = __shfl(idxv, e0, 64);
            int i1 = __shfl(idxv, e1, 64);
            int i2 = __shfl(idxv, e2, 64);
            int i3 = __shfl(idxv, e3, 64);
            int r0 = (e0 < cnt) ? i0 : N_;
            int r1 = (e1 < cnt) ? i1 : N_;
            int r2 = (e2 < cnt) ? i2 : N_;
            int r3 = (e3 < cnt) ? i3 : N_;
            uint4 v0 = ((const uint4*)(xt + (size_t)r0 * D_))[c16];
            uint4 v1 = ((const uint4*)(xt + (size_t)r1 * D_))[c16];
            uint4 v2 = ((const uint4*)(xt + (size_t)r2 * D_))[c16];
            uint4 v3 = ((const uint4*)(xt + (size_t)r3 * D_))[c16];
            accum_row(acc, v0);
            accum_row(acc, v1);
            accum_row(acc, v2);
            accum_row(acc, v3);
        }
        for (; j < steps; ++j) {
            int e0 = 4 * j + g;
            int i0 = __shfl(idxv, e0, 64);
            int r0 = (e0 < cnt) ? i0 : N_;
            uint4 v0 = ((const uint4*)(xt + (size_t)r0 * D_))[c16];
            accum_row(acc, v0);
        }
    }
#pragma unroll
    for (int k = 0; k < 8; ++k) {
        acc[k] += __shfl_xor(acc[k], 16, 64);
        acc[k] += __shfl_xor(acc[k], 32, 64);
    }
    if (g == 0) {
        uint4 o;
        o.x = (unsigned)f2bf(acc[0]) | ((unsigned)f2bf(acc[1]) << 16);
        o.y = (unsigned)f2bf(acc[2]) | ((unsigned)f2bf(acc[3]) << 16);
        o.z = (unsigned)f2bf(acc[4]) | ((unsigned)f2bf(acc[5]) << 16);
        o.w = (unsigned)f2bf(acc[6]) | ((unsigned)f2bf(acc[7]) << 16);
        ((uint4*)(agg + (size_t)pdst * D_))[c16] = o;
    }
}

// ---------------------------------------------------------------------------
// Round 7: HBM-byte diet on fused_layer (R6 lesson: fused is BYTES-bound,
// not gather-latency-bound — contiguity bought nothing).
//   - x' residual stream stored as BF16 (xpb, 12.8MB) instead of fp32
//     (was 25.6MB each way). GEMM3 already consumed bf16 x' (Pl/Ph words),
//     so only the residual-add precision changes (~0.004 abs on O(1) vals).
//     The packed Pl/Ph words ARE the store data — no repack, and the
//     non-LAST fp32 OutF store is gone.
//   - x0p fp32 copy dropped; layer-0 residual and LAST x0-add read input
//     x0 via blist (scattered fp32 — proven cost-free by R6).
// Net: −77MB HBM per run, −38MB workspace. Structure unchanged from R5/R6:
// 8 waves / 512 thr / TM=128 / (512,4) / swapped GEMMs / 5 barriers.
// ---------------------------------------------------------------------------

// stage one 128x128 bf16 matrix into sB, async, 8 waves x 4 segs
__device__ inline void stage_B_async(const unsigned short* __restrict__ B,
                                     unsigned short* sB, int wave, int lane) {
    int rsub = lane >> 4, cl = lane & 15;
#pragma unroll
    for (int j = 0; j < 4; ++j) {
        int seg = wave * 4 + j;
        int row = seg * 4 + rsub;
        GLD16(B + row * 128 + ((cl ^ (row & 15)) << 3), sB + seg * 512);
    }
}

// build bf16x8 B-frag (dims 32kc+8q .. +7 of own row) from packed bf16 pairs
// Pl/Ph (Pl[t] = dims {16t+4q+0,1}, Ph[t] = {+2,+3}) via 4-lane exchange.
#define XCH_FRAG(dst, Pl, Ph, kc)                                            \
    {                                                                        \
        unsigned a0 = __shfl(Pl[2 * (kc)], s0, 64);                          \
        unsigned b0 = __shfl(Pl[2 * (kc) + 1], s0, 64);                      \
        unsigned a1 = __shfl(Ph[2 * (kc)], s0, 64);                          \
        unsigned b1 = __shfl(Ph[2 * (kc) + 1], s0, 64);                      \
        unsigned a2 = __shfl(Pl[2 * (kc)], s1, 64);                          \
        unsigned b2 = __shfl(Pl[2 * (kc) + 1], s1, 64);                      \
        unsigned a3 = __shfl(Ph[2 * (kc)], s1, 64);                          \
        unsigned b3 = __shfl(Ph[2 * (kc) + 1], s1, 64);                      \
        union { unsigned u[4]; bf16x8 v; } fu;                               \
        fu.u[0] = hi ? b0 : a0;                                              \
        fu.u[1] = hi ? b1 : a1;                                              \
        fu.u[2] = hi ? b2 : a2;                                              \
        fu.u[3] = hi ? b3 : a3;                                              \
        dst = fu.v;                                                          \
    }

// ---------------------------------------------------------------------------
// gemm_xt0: xt = xb @ Sb[0][pol], positions contiguous. 1 barrier, no rid.
// ---------------------------------------------------------------------------

__global__ __launch_bounds__(512, 4) void gemm_xt0(
    const unsigned short* __restrict__ A, const unsigned short* __restrict__ Bw,
    unsigned short* __restrict__ OutB,
    const int* __restrict__ boff, const int* __restrict__ tileOff) {
    __shared__ unsigned short sB[128 * 128];
    int tid = threadIdx.x, b = blockIdx.x;
    if (b >= tileOff[P_]) return;
    int pp = 0;
    while (pp < P_ - 1 && b >= tileOff[pp + 1]) ++pp;
    int tb = b - tileOff[pp];
    int cnt = boff[pp + 1] - boff[pp];
    int nrows = min(TM, cnt - tb * TM);
    int rowbase = boff[pp] + tb * TM;

    int lane = tid & 63, wave = tid >> 6;
    int n = lane & 15, q = lane >> 4;
    int rr = wave * 16 + n;
    size_t posr = (size_t)(rowbase + rr);

    stage_B_async(Bw + (size_t)pp * (D_ * D_), sB, wave, lane);
    bf16x8 bg[4];
#pragma unroll
    for (int kc = 0; kc < 4; ++kc)
        bg[kc] = *(const bf16x8*)(A + posr * 128 + kc * 32 + q * 8);
    __syncthreads();  // drains stage + bg

    f32x4 acc[8];
#pragma unroll
    for (int t = 0; t < 8; ++t) acc[t] = (f32x4){0.f, 0.f, 0.f, 0.f};
#pragma unroll
    for (int kc = 0; kc < 4; ++kc) {
#pragma unroll
        for (int t = 0; t < 8; ++t) {
            int cs = ((((kc << 2) + q) ^ n) << 3);
            bf16x8 af = *(const bf16x8*)(sB + (t * 16 + n) * 128 + cs);
            acc[t] = __builtin_amdgcn_mfma_f32_16x16x32_bf16(af, bg[kc], acc[t], 0, 0, 0);
        }
    }
    if (rr < nrows) {
#pragma unroll
        for (int t = 0; t < 8; ++t) {
            uint2 o;
            o.x = pack2bf(acc[t][0], acc[t][1]);
            o.y = pack2bf(acc[t][2], acc[t][3]);
            *(uint2*)(OutB + posr * 128 + t * 16 + q * 4) = o;
        }
    }
}

// ---------------------------------------------------------------------------
// fused_layer (swapped, 8-wave, position layout, bf16 residual):
// GEMM1+LN+relu -> GEMM2+res+LN -> [GEMM3 unless LAST].
// FIRST: residual = x0[blist[pos]] fp32 (input).  !FIRST: residual = xpIn
// bf16 positional.  LAST: adds x0[blist[pos]] and scatters final out.
// ---------------------------------------------------------------------------

template <bool LAST, bool FIRST>
__global__ __launch_bounds__(512, 4) void fused_layer(
    const unsigned short* __restrict__ agg, const unsigned short* __restrict__ DmAll,
    const unsigned short* __restrict__ W2b, const unsigned short* __restrict__ SnAll,
    const int* __restrict__ blist, const int* __restrict__ boff,
    const int* __restrict__ tileOff, const float* __restrict__ dnormp,
    const float* __restrict__ b1v, const float* __restrict__ g1v,
    const float* __restrict__ e1v, const float* __restrict__ b2v,
    const float* __restrict__ g2v, const float* __restrict__ e2v,
    const float* __restrict__ rs_ptr, const float* __restrict__ x0n,
    const unsigned short* __restrict__ xpIn, unsigned short* __restrict__ xpOut,
    float* __restrict__ OutF, unsigned short* __restrict__ OutXt) {
    __shared__ unsigned short sB[128 * 128];  // 32 KiB (Dm -> W2 -> Sn)

    int tid = threadIdx.x, b = blockIdx.x;
    if (b >= tileOff[P_]) return;
    int pp = 0;
    while (pp < P_ - 1 && b >= tileOff[pp + 1]) ++pp;
    int tb = b - tileOff[pp];
    int cnt = boff[pp + 1] - boff[pp];
    int nrows = min(TM, cnt - tb * TM);
    int rowbase = boff[pp] + tb * TM;

    int lane = tid & 63, wave = tid >> 6;
    int n = lane & 15, q = lane >> 4;
    int rr = wave * 16 + n;
    size_t posr = (size_t)(rowbase + rr);
    int s0 = n + ((q & 1) << 5), s1 = s0 + 16;  // exchange partners (q-group)
    bool hi = q >= 2;

    stage_B_async(DmAll + (size_t)pp * (D_ * D_), sB, wave, lane);
    bf16x8 bg[4];
#pragma unroll
    for (int kc = 0; kc < 4; ++kc)
        bg[kc] = *(const bf16x8*)(agg + posr * 128 + kc * 32 + q * 8);
    float dn = dnormp[posr];
    __syncthreads();  // #1: sB(Dm) + bg ready

    // ---- GEMM1: out1^T = Dm^T @ agg^T  (lane holds row posr, d=16t+4q+r) ----
    f32x4 acc[8];
#pragma unroll
    for (int t = 0; t < 8; ++t) acc[t] = (f32x4){0.f, 0.f, 0.f, 0.f};
#pragma unroll
    for (int kc = 0; kc < 4; ++kc) {
#pragma unroll
        for (int t = 0; t < 8; ++t) {
            int cs = ((((kc << 2) + q) ^ n) << 3);
            bf16x8 af = *(const bf16x8*)(sB + (t * 16 + n) * 128 + cs);
            acc[t] = __builtin_amdgcn_mfma_f32_16x16x32_bf16(af, bg[kc], acc[t], 0, 0, 0);
        }
    }

    // ---- LN1 + relu -> h (packed bf16 pairs Pl/Ph) ----
    unsigned Pl[8], Ph[8];
    {
        float rs1 = 0.f, rs2 = 0.f;
#pragma unroll
        for (int t = 0; t < 8; ++t) {
            float4 bb = *(const float4*)(b1v + t * 16 + q * 4);
#pragma unroll
            for (int r = 0; r < 4; ++r) {
                float v = dn * acc[t][r] + (&bb.x)[r];
                acc[t][r] = v;
                rs1 += v;
                rs2 += v * v;
            }
        }
        rs1 += __shfl_xor(rs1, 16, 64);
        rs1 += __shfl_xor(rs1, 32, 64);
        rs2 += __shfl_xor(rs2, 16, 64);
        rs2 += __shfl_xor(rs2, 32, 64);
        float mm = rs1 * (1.f / 128.f);
        float rv = rsqrtf(rs2 * (1.f / 128.f) - mm * mm + EPS_);
#pragma unroll
        for (int t = 0; t < 8; ++t) {
            float4 gg = *(const float4*)(g1v + t * 16 + q * 4);
            float4 ee = *(const float4*)(e1v + t * 16 + q * 4);
            float h0 = fmaxf((acc[t][0] - mm) * rv * gg.x + ee.x, 0.f);
            float h1 = fmaxf((acc[t][1] - mm) * rv * gg.y + ee.y, 0.f);
            float h2 = fmaxf((acc[t][2] - mm) * rv * gg.z + ee.z, 0.f);
            float h3 = fmaxf((acc[t][3] - mm) * rv * gg.w + ee.w, 0.f);
            Pl[t] = pack2bf(h0, h1);
            Ph[t] = pack2bf(h2, h3);
        }
    }

    __syncthreads();                     // #2: sB(Dm) free
    stage_B_async(W2b, sB, wave, lane);  // async; overlapped by exchange
    bf16x8 h2[4];
#pragma unroll
    for (int kc = 0; kc < 4; ++kc) XCH_FRAG(h2[kc], Pl, Ph, kc)
    __syncthreads();  // #3: sB(W2) ready

    // ---- GEMM2: out2^T = W2 @ h^T ----
#pragma unroll
    for (int t = 0; t < 8; ++t) acc[t] = (f32x4){0.f, 0.f, 0.f, 0.f};
#pragma unroll
    for (int kc = 0; kc < 4; ++kc) {
#pragma unroll
        for (int t = 0; t < 8; ++t) {
            int cs = ((((kc << 2) + q) ^ n) << 3);
            bf16x8 af = *(const bf16x8*)(sB + (t * 16 + n) * 128 + cs);
            acc[t] = __builtin_amdgcn_mfma_f32_16x16x32_bf16(af, h2[kc], acc[t], 0, 0, 0);
        }
    }

    // ---- residual + LN2 -> x' ----
    float rsc = rs_ptr[0];
    float xr4[8][4];
    if constexpr (FIRST) {
        int rwl = (rr < nrows) ? blist[posr] : -1;
#pragma unroll
        for (int t = 0; t < 8; ++t) {
            if (rwl >= 0) {
                float4 v = *(const float4*)(x0n + (size_t)rwl * 128 + t * 16 + q * 4);
                xr4[t][0] = v.x; xr4[t][1] = v.y; xr4[t][2] = v.z; xr4[t][3] = v.w;
            } else {
                xr4[t][0] = xr4[t][1] = xr4[t][2] = xr4[t][3] = 0.f;
            }
        }
    } else {
#pragma unroll
        for (int t = 0; t < 8; ++t) {
            uint2 u = *(const uint2*)(xpIn + posr * 128 + t * 16 + q * 4);
            xr4[t][0] = bflo(u.x); xr4[t][1] = bfhi(u.x);
            xr4[t][2] = bflo(u.y); xr4[t][3] = bfhi(u.y);
        }
    }
    {
        float rs1 = 0.f, rs2 = 0.f;
#pragma unroll
        for (int t = 0; t < 8; ++t) {
            float4 bb = *(const float4*)(b2v + t * 16 + q * 4);
#pragma unroll
            for (int r = 0; r < 4; ++r) {
                float v = rsc * (acc[t][r] + (&bb.x)[r]) + xr4[t][r];
                acc[t][r] = v;
                rs1 += v;
                rs2 += v * v;
            }
        }
        rs1 += __shfl_xor(rs1, 16, 64);
        rs1 += __shfl_xor(rs1, 32, 64);
        rs2 += __shfl_xor(rs2, 16, 64);
        rs2 += __shfl_xor(rs2, 32, 64);
        float mm = rs1 * (1.f / 128.f);
        float rv = rsqrtf(rs2 * (1.f / 128.f) - mm * mm + EPS_);
        if constexpr (LAST) {
            int rwl = (rr < nrows) ? blist[posr] : -1;
#pragma unroll
            for (int t = 0; t < 8; ++t) {
                float4 gg = *(const float4*)(g2v + t * 16 + q * 4);
                float4 ee = *(const float4*)(e2v + t * 16 + q * 4);
                if (rwl >= 0) {
                    float4 xa = *(const float4*)(x0n + (size_t)rwl * 128 + t * 16 + q * 4);
                    float4 o;
                    o.x = (acc[t][0] - mm) * rv * gg.x + ee.x + xa.x;
                    o.y = (acc[t][1] - mm) * rv * gg.y + ee.y + xa.y;
                    o.z = (acc[t][2] - mm) * rv * gg.z + ee.z + xa.z;
                    o.w = (acc[t][3] - mm) * rv * gg.w + ee.w + xa.w;
                    *(float4*)(OutF + (size_t)rwl * 128 + t * 16 + q * 4) = o;
                }
            }
        } else {
#pragma unroll
            for (int t = 0; t < 8; ++t) {
                float4 gg = *(const float4*)(g2v + t * 16 + q * 4);
                float4 ee = *(const float4*)(e2v + t * 16 + q * 4);
                float o0 = (acc[t][0] - mm) * rv * gg.x + ee.x;
                float o1 = (acc[t][1] - mm) * rv * gg.y + ee.y;
                float o2 = (acc[t][2] - mm) * rv * gg.z + ee.z;
                float o3 = (acc[t][3] - mm) * rv * gg.w + ee.w;
                Pl[t] = pack2bf(o0, o1);
                Ph[t] = pack2bf(o2, o3);
            }
        }
    }

    if constexpr (!LAST) {
        __syncthreads();  // #4: sB(W2) free
        stage_B_async(SnAll + (size_t)pp * (D_ * D_), sB, wave, lane);
        bf16x8 x2[4];
#pragma unroll
        for (int kc = 0; kc < 4; ++kc) XCH_FRAG(x2[kc], Pl, Ph, kc)
        __syncthreads();  // #5: sB(Sn) ready

        // ---- GEMM3: xt^T = Sn^T @ x'^T ----
#pragma unroll
        for (int t = 0; t < 8; ++t) acc[t] = (f32x4){0.f, 0.f, 0.f, 0.f};
#pragma unroll
        for (int kc = 0; kc < 4; ++kc) {
#pragma unroll
            for (int t = 0; t < 8; ++t) {
                int cs = ((((kc << 2) + q) ^ n) << 3);
                bf16x8 af = *(const bf16x8*)(sB + (t * 16 + n) * 128 + cs);
                acc[t] = __builtin_amdgcn_mfma_f32_16x16x32_bf16(af, x2[kc], acc[t], 0, 0, 0);
            }
        }
        if (rr < nrows) {
#pragma unroll
            for (int t = 0; t < 8; ++t) {
                uint2 o;
                o.x = pack2bf(acc[t][0], acc[t][1]);
                o.y = pack2bf(acc[t][2], acc[t][3]);
                *(uint2*)(OutXt + posr * 128 + t * 16 + q * 4) = o;
            }
            // bf16 x' store (residual stream for next layer) — Pl/Ph are
            // already the packed words; 12.8MB vs 25.6MB fp32.
#pragma unroll
            for (int t = 0; t < 8; ++t) {
                uint2 h;
                h.x = Pl[t];
                h.y = Ph[t];
                *(uint2*)(xpOut + posr * 128 + t * 16 + q * 4) = h;
            }
        }
    }
}

// ---------------------------------------------------------------------------
// Host launch
// ---------------------------------------------------------------------------

extern "C" void kernel_launch(void* const* d_in, const int* in_sizes, int n_in,
                              void* d_out, int out_size, void* d_ws, size_t ws_size,
                              hipStream_t stream) {
    const float* x0 = (const float*)d_in[0];
    const int* ei = (const int*)d_in[1];
    const int* ring = (const int*)d_in[2];
    const float* Wr = (const float*)d_in[3];
    const float* S = (const float*)d_in[4];
    const float* dS = (const float*)d_in[5];
    const float* R = (const float*)d_in[6];
    const float* dR = (const float*)d_in[7];
    const float* rsc = (const float*)d_in[8];
    const float* W1 = (const float*)d_in[9];
    const float* b1 = (const float*)d_in[10];
    const float* lng = (const float*)d_in[11];
    const float* lnb = (const float*)d_in[12];
    const float* W2 = (const float*)d_in[13];
    const float* b2 = (const float*)d_in[14];
    const float* ng = (const float*)d_in[15];
    const float* nb = (const float*)d_in[16];
    float* out = (float*)d_out;

    char* w = (char*)d_ws;
    auto alloc = [&](size_t bytes) {
        char* p = w;
        w += (bytes + 15) & ~(size_t)15;
        return p;
    };
    const size_t NP = (size_t)N_ + TM + 1;  // padded row count (pos space)
    unsigned short* xb = (unsigned short*)alloc(NP * D_ * 2);     // bf16 x0, pos order (+pad)
    unsigned short* bufAb = (unsigned short*)alloc(NP * D_ * 2);  // xt, pos order (+zero row N)
    unsigned short* bufBb = (unsigned short*)alloc(NP * D_ * 2);  // agg, pos order (+zero row N)
    unsigned short* xpb = (unsigned short*)alloc(NP * D_ * 2);    // bf16 x', pos order
    unsigned short* Sb = (unsigned short*)alloc((size_t)L_ * P_ * D_ * D_ * 2);
    unsigned short* Dmb = (unsigned short*)alloc((size_t)L_ * P_ * D_ * D_ * 2);
    unsigned short* W2b = (unsigned short*)alloc((size_t)L_ * D_ * D_ * 2);
    unsigned short* Arh = (unsigned short*)alloc((size_t)MAT * 16384 * 2);
    unsigned short* Arl = (unsigned short*)alloc((size_t)MAT * 16384 * 2);
    unsigned short* W1h = (unsigned short*)alloc((size_t)3 * 16384 * 2);
    unsigned short* W1l = (unsigned short*)alloc((size_t)3 * 16384 * 2);
    unsigned short* Wrth = (unsigned short*)alloc((size_t)3 * 16384 * 2);
    unsigned short* Wrtl = (unsigned short*)alloc((size_t)3 * 16384 * 2);
    unsigned short* T1th = (unsigned short*)alloc((size_t)MAT * 16384 * 2);
    unsigned short* T1tl = (unsigned short*)alloc((size_t)MAT * 16384 * 2);
    float* dnormp = (float*)alloc(NP * 4);  // pos order
    int* histG = (int*)alloc((size_t)HTOT * 4);
    unsigned* bufT = (unsigned*)alloc((size_t)E_ * 4);
    unsigned char* bufS8 = (unsigned char*)alloc((size_t)E_);
    unsigned short* eSrc = (unsigned short*)alloc((size_t)E_ * 2);
    int* offT = (int*)alloc((size_t)(N_ + 1) * 4);
    int* pol = (int*)alloc((size_t)N_ * 4);
    int* boff = (int*)alloc((size_t)(P_ + 1) * 4);
    int* tileOff = (int*)alloc((size_t)(P_ + 1) * 4);
    int* blist = (int*)alloc(NP * 4);
    int* perm = (int*)alloc((size_t)N_ * 4);
    int* blkSum = (int*)alloc((size_t)NSB * 4);
    int* blkOff = (int*)alloc((size_t)NSB * 4);
    int* bcnt = (int*)alloc((size_t)2 * P_ * 4);  // zeroed region: bcnt + bcur
    int* bcur = bcnt + P_;

    hipMemsetAsync(bcnt, 0, (size_t)2 * P_ * 4, stream);

    const int BTILES = N_ / TM + P_;  // 399, upper bound on bucketed tiles

    setup_nk<<<NBK, 256, 0, stream>>>(ring, pol, bcnt, ei, histG);
    scanH1<<<NSB, 1024, 0, stream>>>(histG, blkSum);
    scanH2<<<1, 64, 0, stream>>>(blkSum, blkOff, offT, bcnt, boff, tileOff);
    scanH3<<<NSB, 1024, 0, stream>>>(histG, blkOff);
    scatterTS<<<NBK + NBUK, 256, 0, stream>>>(ei, histG, bufT, bufS8,
                                              pol, boff, bcur, blist, perm);
    finalize3<<<2 * NBUK, 256, 0, stream>>>(bufT, bufS8, histG, offT, eSrc,
                                            dnormp, perm);
    prep_all<<<GPREP, 256, 0, stream>>>(x0, xb, perm, bufAb, bufBb,
                                        S, dS, Sb, W2, W2b,
                                        R, dR, W1, Wr, Arh, Arl, W1h, W1l, Wrth, Wrtl);
    // T1t[mat][k][i] = sum_j W1[l][k][j] * (R+dR)[mat][i][j]
    small_mfma<false, true, true><<<2 * MAT, 256, 0, stream>>>(
        W1h, W1l, Arh, Arl, T1th, T1tl);
    // Dmb[mat][k][d] = sum_i T1t[mat][k][i] * Wr^T[l][d][i]
    small_mfma<true, false, false><<<2 * MAT, 256, 0, stream>>>(
        T1th, T1tl, Wrth, Wrtl, Dmb, nullptr);

    // layer 0 send-transform: xt0 = x0 @ (S+dS)[0][pol], position space
    gemm_xt0<<<BTILES, 512, 0, stream>>>(xb, Sb, bufAb, boff, tileOff);

    for (int l = 0; l < L_; ++l) {
        const size_t lPDD = (size_t)l * P_ * D_ * D_;
        const size_t lDD = (size_t)l * D_ * D_;
        const size_t lD = (size_t)l * D_;
        aggregate_bf<<<N_ / 4, 256, 0, stream>>>(bufAb, offT, eSrc, perm, bufBb);
        if (l == 0) {
            fused_layer<false, true><<<BTILES, 512, 0, stream>>>(
                bufBb, Dmb + lPDD, W2b + lDD, Sb + lPDD + (size_t)P_ * D_ * D_,
                blist, boff, tileOff, dnormp,
                b1 + lD, lng + lD, lnb + lD, b2 + lD, ng + lD, nb + lD,
                rsc + l, x0, nullptr, xpb, nullptr, bufAb);
        } else if (l < L_ - 1) {
            fused_layer<false, false><<<BTILES, 512, 0, stream>>>(
                bufBb, Dmb + lPDD, W2b + lDD, Sb + lPDD + (size_t)P_ * D_ * D_,
                blist, boff, tileOff, dnormp,
                b1 + lD, lng + lD, lnb + lD, b2 + lD, ng + lD, nb + lD,
                rsc + l, nullptr, xpb, xpb, nullptr, bufAb);
        } else {
            fused_layer<true, false><<<BTILES, 512, 0, stream>>>(
                bufBb, Dmb + lPDD, W2b + lDD, nullptr,
                blist, boff, tileOff, dnormp,
                b1 + lD, lng + lD, lnb + lD, b2 + lD, ng + lD, nb + lD,
                rsc + l, x0, xpb, nullptr, out, nullptr);
        }
    }
}

// Round 8
// 360.071 us; speedup vs baseline: 1.0342x; 1.0211x over previous
//
#include <hip/hip_runtime.h>
#include <hip/hip_bf16.h>

// Problem constants
constexpr int N_ = 50000;
constexpr int D_ = 128;
constexpr int E_ = 800000;
constexpr int P_ = 9;
constexpr int L_ = 3;
constexpr float EPS_ = 1e-5f;

constexpr int TM = 128;   // rows per GEMM block (8 waves x 16 rows)
constexpr int CHUNK = 4096;                    // edges per hist/scatter block
constexpr int NBK = (E_ + CHUNK - 1) / CHUNK;  // 196 edge chunks
constexpr int NBUK = 196;                      // node buckets (50000>>8 = 195 max)
constexpr int HHALF = 256 * NBK;               // 50176 (per-half hist size)
constexpr int HTOT = 2 * HHALF;                // 100352 = 98 * 1024 exactly
constexpr int NSB = HTOT / 1024;               // 98 scan blocks
constexpr int MAT = L_ * P_;                   // 27 small matrices

typedef short bf16x8 __attribute__((ext_vector_type(8)));
typedef float f32x4 __attribute__((ext_vector_type(4)));

// async 16B global->LDS copy; lds base must be wave-uniform, data lands at
// base + lane*16  [guide §5, m97]
#define GLD16(gp, lp)                                                        \
    __builtin_amdgcn_global_load_lds(                                        \
        (const __attribute__((address_space(1))) unsigned int*)(gp),         \
        (__attribute__((address_space(3))) unsigned int*)(lp), 16, 0, 0)

__device__ inline unsigned short f2bf(float f) {
    __hip_bfloat16 h = __float2bfloat16(f);
    return *reinterpret_cast<unsigned short*>(&h);
}
__device__ inline float bflo(unsigned u) { return __uint_as_float(u << 16); }
__device__ inline float bfhi(unsigned u) { return __uint_as_float(u & 0xffff0000u); }
__device__ inline float bf2f(unsigned short h) {
    return __uint_as_float((unsigned)h << 16);
}
__device__ inline unsigned pack2bf(float a, float b) {
    return (unsigned)f2bf(a) | ((unsigned)f2bf(b) << 16);
}

// ---------------------------------------------------------------------------
// setup_nk: node polarity init + edge histograms (merged)
// ---------------------------------------------------------------------------

__global__ __launch_bounds__(256) void setup_nk(const int* __restrict__ ring,
                                                int* __restrict__ pol,
                                                int* __restrict__ bcnt,
                                                const int* __restrict__ ei,
                                                int* __restrict__ histG) {
    __shared__ int h[P_];
    __shared__ int hT[256], hS[256];
    int blk = blockIdx.x, tid = threadIdx.x;
    if (tid < P_) h[tid] = 0;
    hT[tid] = 0;
    hS[tid] = 0;
    __syncthreads();
    int n = blk * 256 + tid;
    if (n < N_) {
        int p = ring[n] % P_;
        pol[n] = p;
        atomicAdd(&h[p], 1);
    }
    int base = blk * CHUNK;
#pragma unroll
    for (int i = 0; i < CHUNK / 256; ++i) {
        int e = base + tid + i * 256;
        if (e < E_) {
            atomicAdd(&hS[ei[e] >> 8], 1);
            atomicAdd(&hT[ei[E_ + e] >> 8], 1);
        }
    }
    __syncthreads();
    if (tid < P_ && h[tid] > 0) atomicAdd(&bcnt[tid], h[tid]);
    histG[tid * NBK + blk] = hT[tid];
    histG[HHALF + tid * NBK + blk] = hS[tid];
}

// ---------------------------------------------------------------------------
// 3-phase exclusive scan of histG[HTOT]
// ---------------------------------------------------------------------------

__global__ __launch_bounds__(1024) void scanH1(int* __restrict__ a,
                                               int* __restrict__ blkSum) {
    __shared__ int wsum[16];
    int tid = threadIdx.x, lane = tid & 63, wid = tid >> 6;
    int idx = blockIdx.x * 1024 + tid;
    int v = a[idx];
    int inc = v;
#pragma unroll
    for (int o = 1; o < 64; o <<= 1) {
        int t = __shfl_up(inc, o, 64);
        if (lane >= o) inc += t;
    }
    if (lane == 63) wsum[wid] = inc;
    __syncthreads();
    if (tid < 16) {
        int s = wsum[tid];
#pragma unroll
        for (int o = 1; o < 16; o <<= 1) {
            int t = __shfl_up(s, o, 64);
            if (tid >= o) s += t;
        }
        wsum[tid] = s;
    }
    __syncthreads();
    int wexcl = (wid == 0) ? 0 : wsum[wid - 1];
    a[idx] = wexcl + inc - v;
    if (tid == 1023) blkSum[blockIdx.x] = wsum[15];
}

__global__ void scanH2(const int* __restrict__ blkSum, int* __restrict__ blkOff,
                       int* __restrict__ offT, const int* __restrict__ bcnt,
                       int* __restrict__ boff, int* __restrict__ tileOff) {
    if (threadIdx.x != 0) return;
    int run = 0;
    for (int i = 0; i < NSB; ++i) {
        blkOff[i] = run;
        run += blkSum[i];
    }
    offT[N_] = E_;
    boff[0] = 0;
    tileOff[0] = 0;
    for (int p = 0; p < P_; ++p) {
        boff[p + 1] = boff[p] + bcnt[p];
        tileOff[p + 1] = tileOff[p] + (bcnt[p] + TM - 1) / TM;
    }
}

__global__ __launch_bounds__(1024) void scanH3(int* __restrict__ a,
                                               const int* __restrict__ blkOff) {
    int idx = blockIdx.x * 1024 + threadIdx.x;
    a[idx] += blkOff[blockIdx.x];
}

// ---------------------------------------------------------------------------
// scatter into tgt-buckets (packed) and src-buckets (low byte)
// ---------------------------------------------------------------------------

__global__ __launch_bounds__(256) void scatterTS(const int* __restrict__ ei,
                                                 const int* __restrict__ histG,
                                                 unsigned* __restrict__ bufT,
                                                 unsigned char* __restrict__ bufS8) {
    __shared__ int ldsT[256], ldsS[256];
    int blk = blockIdx.x, tid = threadIdx.x;
    ldsT[tid] = histG[tid * NBK + blk];
    ldsS[tid] = histG[HHALF + tid * NBK + blk] - E_;
    __syncthreads();
    int base = blk * CHUNK;
#pragma unroll
    for (int i = 0; i < CHUNK / 256; ++i) {
        int e = base + tid + i * 256;
        if (e < E_) {
            int s = ei[e], t = ei[E_ + e];
            int pT = atomicAdd(&ldsT[t >> 8], 1);
            bufT[pT] = ((unsigned)t << 16) | (unsigned)s;
            int pS = atomicAdd(&ldsS[s >> 8], 1);
            bufS8[pS] = (unsigned char)(s & 255);
        }
    }
}

// ---------------------------------------------------------------------------
// finalize3: finalizeT | finalizeS | bucket_fill (role by blockIdx)
// ---------------------------------------------------------------------------

__global__ __launch_bounds__(256) void finalize3(
    const unsigned* __restrict__ bufT, const unsigned char* __restrict__ bufS8,
    const int* __restrict__ histG, int* __restrict__ offT,
    unsigned short* __restrict__ eSrc, float* __restrict__ dnorm,
    const int* __restrict__ pol, const int* __restrict__ boff,
    int* __restrict__ bcur, int* __restrict__ blist) {
    __shared__ int s0[256];
    __shared__ int s1[256];
    int bb = blockIdx.x, tid = threadIdx.x;

    if (bb < NBUK) {
        int b = bb;
        int start = histG[b * NBK];
        int end = histG[(b + 1) * NBK];
        s0[tid] = 0;
        __syncthreads();
        for (int i = start + tid; i < end; i += 256)
            atomicAdd(&s0[(bufT[i] >> 16) & 255], 1);
        __syncthreads();
        if (tid < 64) {
            int b0 = 4 * tid;
            int v0 = s0[b0], v1 = s0[b0 + 1], v2 = s0[b0 + 2], v3 = s0[b0 + 3];
            int lsum = v0 + v1 + v2 + v3;
            int inc = lsum;
#pragma unroll
            for (int o = 1; o < 64; o <<= 1) {
                int t = __shfl_up(inc, o, 64);
                if (tid >= o) inc += t;
            }
            int excl = inc - lsum;
            s1[b0] = excl;
            s1[b0 + 1] = excl + v0;
            s1[b0 + 2] = excl + v0 + v1;
            s1[b0 + 3] = excl + v0 + v1 + v2;
        }
        __syncthreads();
        int node = (b << 8) + tid;
        if (node < N_) offT[node] = start + s1[tid];
        __syncthreads();
        for (int i = start + tid; i < end; i += 256) {
            unsigned pk = bufT[i];
            int pos = start + atomicAdd(&s1[(pk >> 16) & 255], 1);
            eSrc[pos] = (unsigned short)(pk & 0xFFFF);
        }
    } else if (bb < 2 * NBUK) {
        int b = bb - NBUK;
        int start = histG[HHALF + b * NBK] - E_;
        int end = histG[HHALF + (b + 1) * NBK] - E_;
        s0[tid] = 0;
        __syncthreads();
        for (int i = start + tid; i < end; i += 256) atomicAdd(&s0[bufS8[i]], 1);
        __syncthreads();
        int node = (b << 8) + tid;
        if (node < N_) {
            int dg = s0[tid];
            dnorm[node] = 1.f / (float)(dg > 1 ? dg : 1);
        }
    } else {
        int b = bb - 2 * NBUK;
        if (tid < P_) s0[tid] = 0;
        __syncthreads();
        int n = b * 256 + tid;
        int p = 0, loc = 0;
        bool act = (n < N_);
        if (act) {
            p = pol[n];
            loc = atomicAdd(&s0[p], 1);
        }
        __syncthreads();
        if (tid < P_ && s0[tid] > 0) s1[tid] = atomicAdd(&bcur[tid], s0[tid]);
        __syncthreads();
        if (act) blist[boff[p] + s1[p] + loc] = n;
    }
}

// ---------------------------------------------------------------------------
// prep_all: conv4 | zero rows | prep_S | prep_W2 | prep_split merged
// (node order — R6/R7 position permute reverted: it serialized prep behind
// the edge pipeline and scattered prep's writes, for no measured gain)
// ---------------------------------------------------------------------------

constexpr int GCONV = N_ * D_ / 4 / 256;       // 6250
constexpr int GS = L_ * P_ * D_ * D_ / 256;    // 1728
constexpr int GW2 = L_ * D_ * D_ / 256;        // 192
constexpr int GSPL = (MAT + 6) * 16384 / 256;  // 2112
constexpr int GPREP = GCONV + 1 + GS + GW2 + GSPL;

__global__ __launch_bounds__(256) void prep_all(
    const float* __restrict__ x, unsigned short* __restrict__ xb,
    unsigned short* __restrict__ bufAb, unsigned short* __restrict__ bufBb,
    const float* __restrict__ S, const float* __restrict__ dS,
    unsigned short* __restrict__ Sb,
    const float* __restrict__ W2, unsigned short* __restrict__ W2b,
    const float* __restrict__ R, const float* __restrict__ dR,
    const float* __restrict__ W1, const float* __restrict__ Wr,
    unsigned short* __restrict__ Arh, unsigned short* __restrict__ Arl,
    unsigned short* __restrict__ W1h, unsigned short* __restrict__ W1l,
    unsigned short* __restrict__ Wrth, unsigned short* __restrict__ Wrtl) {
    int b = blockIdx.x, tid = threadIdx.x;
    if (b < GCONV) {
        int i = b * 256 + tid;
        float4 v = ((const float4*)x)[i];
        ushort4 o;
        o.x = f2bf(v.x); o.y = f2bf(v.y); o.z = f2bf(v.z); o.w = f2bf(v.w);
        ((ushort4*)xb)[i] = o;
    } else if (b < GCONV + 1) {
        if (tid < 64) {
            ((unsigned*)(xb + (size_t)N_ * D_))[tid] = 0;
            ((unsigned*)(bufAb + (size_t)N_ * D_))[tid] = 0;
            ((unsigned*)(bufBb + (size_t)N_ * D_))[tid] = 0;
        }
    } else if (b < GCONV + 1 + GS) {
        int idx = (b - GCONV - 1) * 256 + tid;
        int base = idx / (D_ * D_);
        int rem = idx % (D_ * D_);
        int c = rem / D_, d = rem % D_;
        size_t in = (size_t)base * D_ * D_ + (size_t)d * D_ + c;
        Sb[idx] = f2bf(S[in] + dS[in]);
    } else if (b < GCONV + 1 + GS + GW2) {
        int idx = (b - GCONV - 1 - GS) * 256 + tid;
        W2b[idx] = f2bf(W2[idx]);
    } else {
        constexpr int SZ1 = MAT * 16384;
        constexpr int SZ2 = SZ1 + 3 * 16384;
        int idx = (b - GCONV - 1 - GS - GW2) * 256 + tid;
        float v;
        unsigned short* oh;
        unsigned short* ol;
        int j;
        if (idx < SZ1) {
            v = R[idx] + dR[idx];
            oh = Arh; ol = Arl; j = idx;
        } else if (idx < SZ2) {
            j = idx - SZ1;
            v = W1[j];
            oh = W1h; ol = W1l;
        } else {
            j = idx - SZ2;
            int l = j >> 14, rem = j & 16383;
            int d = rem >> 7, i = rem & 127;
            v = Wr[(l << 14) + i * 128 + d];
            oh = Wrth; ol = Wrtl;
        }
        unsigned short h = f2bf(v);
        oh[j] = h;
        ol[j] = f2bf(v - bf2f(h));
    }
}

// ---------------------------------------------------------------------------
// Batched small MFMA GEMM (fp32-equivalent via 2-term bf16 split)
// ---------------------------------------------------------------------------

template <bool APM, bool BPM, bool OUT_SPLIT>
__global__ __launch_bounds__(256) void small_mfma(
    const unsigned short* __restrict__ Ah, const unsigned short* __restrict__ Al,
    const unsigned short* __restrict__ Bh, const unsigned short* __restrict__ Bl,
    unsigned short* __restrict__ Oh, unsigned short* __restrict__ Ol) {
    __shared__ unsigned short stg[(OUT_SPLIT ? 2 : 1) * 64 * 136];
    int tid = threadIdx.x, b = blockIdx.x;
    int mat = b >> 1, rb = b & 1;
    int l = mat / P_;
    size_t aoff = (size_t)(APM ? mat : l) * 16384 + (size_t)rb * 8192;
    size_t boff = (size_t)(BPM ? mat : l) * 16384;
    const unsigned short* ahp = Ah + aoff;
    const unsigned short* alp = Al + aoff;
    const unsigned short* bhp = Bh + boff;
    const unsigned short* blp = Bl + boff;

    int lane = tid & 63, wave = tid >> 6;
    int n = lane & 15, q = lane >> 4;
    int wr = wave * 16;

    f32x4 acc[8];
#pragma unroll
    for (int t = 0; t < 8; ++t) acc[t] = (f32x4){0.f, 0.f, 0.f, 0.f};

    int arow = (wr + n) * 128;
#pragma unroll
    for (int kc = 0; kc < 4; ++kc) {
        int ko = kc * 32 + q * 8;
        bf16x8 avh = *(const bf16x8*)(ahp + arow + ko);
        bf16x8 avl = *(const bf16x8*)(alp + arow + ko);
#pragma unroll
        for (int t = 0; t < 8; ++t) {
            int brow = (t * 16 + n) * 128;
            bf16x8 bvh = *(const bf16x8*)(bhp + brow + ko);
            bf16x8 bvl = *(const bf16x8*)(blp + brow + ko);
            acc[t] = __builtin_amdgcn_mfma_f32_16x16x32_bf16(avh, bvh, acc[t], 0, 0, 0);
            acc[t] = __builtin_amdgcn_mfma_f32_16x16x32_bf16(avh, bvl, acc[t], 0, 0, 0);
            acc[t] = __builtin_amdgcn_mfma_f32_16x16x32_bf16(avl, bvh, acc[t], 0, 0, 0);
        }
    }
#pragma unroll
    for (int t = 0; t < 8; ++t)
#pragma unroll
        for (int r = 0; r < 4; ++r) {
            int row = wr + q * 4 + r;
            float v = acc[t][r];
            unsigned short h = f2bf(v);
            stg[row * 136 + t * 16 + n] = h;
            if constexpr (OUT_SPLIT)
                stg[64 * 136 + row * 136 + t * 16 + n] = f2bf(v - bf2f(h));
        }
    __syncthreads();
    size_t obase = (size_t)mat * 16384 + (size_t)rb * 8192;
#pragma unroll
    for (int i = 0; i < 4; ++i) {
        int c = tid + i * 256;
        int r = c >> 4, off = c & 15;
        *(uint4*)(Oh + obase + r * 128 + off * 8) =
            *(const uint4*)(stg + r * 136 + off * 8);
        if constexpr (OUT_SPLIT)
            *(uint4*)(Ol + obase + r * 128 + off * 8) =
                *(const uint4*)(stg + 64 * 136 + r * 136 + off * 8);
    }
}

// ---------------------------------------------------------------------------
// CSR aggregation: 4 dwordx4 gathers in flight, lane-preloaded indices
// ---------------------------------------------------------------------------

__device__ inline void accum_row(float* acc, uint4 r) {
    acc[0] += bflo(r.x); acc[1] += bfhi(r.x);
    acc[2] += bflo(r.y); acc[3] += bfhi(r.y);
    acc[4] += bflo(r.z); acc[5] += bfhi(r.z);
    acc[6] += bflo(r.w); acc[7] += bfhi(r.w);
}

__global__ __launch_bounds__(256) void aggregate_bf(const unsigned short* __restrict__ xt,
                                                    const int* __restrict__ offT,
                                                    const unsigned short* __restrict__ eSrc,
                                                    unsigned short* __restrict__ agg) {
    int nd = blockIdx.x * 4 + (threadIdx.x >> 6);
    if (nd >= N_) return;
    int l = threadIdx.x & 63;
    int g = l >> 4, c16 = l & 15;
    int beg = offT[nd], end = offT[nd + 1];

    float acc[8];
#pragma unroll
    for (int k = 0; k < 8; ++k) acc[k] = 0.f;

    for (int base = beg; base < end; base += 64) {
        int cnt = min(64, end - base);
        int idxv = (l < cnt) ? (int)eSrc[base + l] : 0;
        int steps = (cnt + 3) >> 2;
        int j = 0;
        for (; j + 3 < steps; j += 4) {
            int e0 = 4 * j + g, e1 = e0 + 4, e2 = e0 + 8, e3 = e0 + 12;
            int i0 = __shfl(idxv, e0, 64);
            int i1 = __shfl(idxv, e1, 64);
            int i2 = __shfl(idxv, e2, 64);
            int i3 = __shfl(idxv, e3, 64);
            int r0 = (e0 < cnt) ? i0 : N_;
            int r1 = (e1 < cnt) ? i1 : N_;
            int r2 = (e2 < cnt) ? i2 : N_;
            int r3 = (e3 < cnt) ? i3 : N_;
            uint4 v0 = ((const uint4*)(xt + (size_t)r0 * D_))[c16];
            uint4 v1 = ((const uint4*)(xt + (size_t)r1 * D_))[c16];
            uint4 v2 = ((const uint4*)(xt + (size_t)r2 * D_))[c16];
            uint4 v3 = ((const uint4*)(xt + (size_t)r3 * D_))[c16];
            accum_row(acc, v0);
            accum_row(acc, v1);
            accum_row(acc, v2);
            accum_row(acc, v3);
        }
        for (; j < steps; ++j) {
            int e0 = 4 * j + g;
            int i0 = __shfl(idxv, e0, 64);
            int r0 = (e0 < cnt) ? i0 : N_;
            uint4 v0 = ((const uint4*)(xt + (size_t)r0 * D_))[c16];
            accum_row(acc, v0);
        }
    }
#pragma unroll
    for (int k = 0; k < 8; ++k) {
        acc[k] += __shfl_xor(acc[k], 16, 64);
        acc[k] += __shfl_xor(acc[k], 32, 64);
    }
    if (g == 0) {
        uint4 o;
        o.x = (unsigned)f2bf(acc[0]) | ((unsigned)f2bf(acc[1]) << 16);
        o.y = (unsigned)f2bf(acc[2]) | ((unsigned)f2bf(acc[3]) << 16);
        o.z = (unsigned)f2bf(acc[4]) | ((unsigned)f2bf(acc[5]) << 16);
        o.w = (unsigned)f2bf(acc[6]) | ((unsigned)f2bf(acc[7]) << 16);
        ((uint4*)(agg + (size_t)nd * D_))[c16] = o;
    }
}

// ---------------------------------------------------------------------------
// Round 8 = R5 structure + R7 byte diet (recombination of proven pieces):
//   R5 base (363.5us, best): node-order buffers, 8 waves / 512 thr / TM=128 /
//   (512,4), swapped GEMMs, register-resident node rows, rid/blist gathers.
//   R6/R7's position layout REVERTED (measured neutral-to-negative: prep
//   serialized behind edge pipeline, scattered prep writes, no fused gain —
//   fused is latency-bound, not gather-bound).
//   R7's diet KEPT (measured byte-correct, absmax unchanged 0.0625):
//     - x' residual stream bf16 (xpb; Pl/Ph packed words stored directly
//       after GEMM3; fp32 OutF store for non-LAST deleted): -51MB
//     - no x0 fp32 copy; layer-0 residual & LAST x0-add gather input x0
//       via rowid (R6 proved gather-vs-stream is a wash): -26MB
// ---------------------------------------------------------------------------

// stage one 128x128 bf16 matrix into sB, async, 8 waves x 4 segs
__device__ inline void stage_B_async(const unsigned short* __restrict__ B,
                                     unsigned short* sB, int wave, int lane) {
    int rsub = lane >> 4, cl = lane & 15;
#pragma unroll
    for (int j = 0; j < 4; ++j) {
        int seg = wave * 4 + j;
        int row = seg * 4 + rsub;
        GLD16(B + row * 128 + ((cl ^ (row & 15)) << 3), sB + seg * 512);
    }
}

// build bf16x8 B-frag (dims 32kc+8q .. +7 of own row) from packed bf16 pairs
// Pl/Ph (Pl[t] = dims {16t+4q+0,1}, Ph[t] = {+2,+3}) via 4-lane exchange.
#define XCH_FRAG(dst, Pl, Ph, kc)                                            \
    {                                                                        \
        unsigned a0 = __shfl(Pl[2 * (kc)], s0, 64);                          \
        unsigned b0 = __shfl(Pl[2 * (kc) + 1], s0, 64);                      \
        unsigned a1 = __shfl(Ph[2 * (kc)], s0, 64);                          \
        unsigned b1 = __shfl(Ph[2 * (kc) + 1], s0, 64);                      \
        unsigned a2 = __shfl(Pl[2 * (kc)], s1, 64);                          \
        unsigned b2 = __shfl(Pl[2 * (kc) + 1], s1, 64);                      \
        unsigned a3 = __shfl(Ph[2 * (kc)], s1, 64);                          \
        unsigned b3 = __shfl(Ph[2 * (kc) + 1], s1, 64);                      \
        union { unsigned u[4]; bf16x8 v; } fu;                               \
        fu.u[0] = hi ? b0 : a0;                                              \
        fu.u[1] = hi ? b1 : a1;                                              \
        fu.u[2] = hi ? b2 : a2;                                              \
        fu.u[3] = hi ? b3 : a3;                                              \
        dst = fu.v;                                                          \
    }

// ---------------------------------------------------------------------------
// gemm_xt0: xt = xb @ Sb[0][pol], bucketed. Swapped form, 1 barrier, no sA.
// ---------------------------------------------------------------------------

__global__ __launch_bounds__(512, 4) void gemm_xt0(
    const unsigned short* __restrict__ A, const unsigned short* __restrict__ Bw,
    unsigned short* __restrict__ OutB, const int* __restrict__ blist,
    const int* __restrict__ boff, const int* __restrict__ tileOff) {
    __shared__ unsigned short sB[128 * 128];
    int tid = threadIdx.x, b = blockIdx.x;
    if (b >= tileOff[P_]) return;
    int pp = 0;
    while (pp < P_ - 1 && b >= tileOff[pp + 1]) ++pp;
    int tb = b - tileOff[pp];
    int cnt = boff[pp + 1] - boff[pp];
    int nrows = min(TM, cnt - tb * TM);
    int rowbase = boff[pp] + tb * TM;

    int lane = tid & 63, wave = tid >> 6;
    int n = lane & 15, q = lane >> 4;
    int rr = wave * 16 + n;
    int rw = (rr < nrows) ? blist[rowbase + rr] : -1;
    size_t grow = (rw >= 0) ? (size_t)rw : (size_t)N_;

    stage_B_async(Bw + (size_t)pp * (D_ * D_), sB, wave, lane);
    bf16x8 bg[4];
#pragma unroll
    for (int kc = 0; kc < 4; ++kc)
        bg[kc] = *(const bf16x8*)(A + grow * 128 + kc * 32 + q * 8);
    __syncthreads();  // drains stage + bg

    f32x4 acc[8];
#pragma unroll
    for (int t = 0; t < 8; ++t) acc[t] = (f32x4){0.f, 0.f, 0.f, 0.f};
#pragma unroll
    for (int kc = 0; kc < 4; ++kc) {
#pragma unroll
        for (int t = 0; t < 8; ++t) {
            int cs = ((((kc << 2) + q) ^ n) << 3);
            bf16x8 af = *(const bf16x8*)(sB + (t * 16 + n) * 128 + cs);
            acc[t] = __builtin_amdgcn_mfma_f32_16x16x32_bf16(af, bg[kc], acc[t], 0, 0, 0);
        }
    }
    if (rw >= 0) {
#pragma unroll
        for (int t = 0; t < 8; ++t) {
            uint2 o;
            o.x = pack2bf(acc[t][0], acc[t][1]);
            o.y = pack2bf(acc[t][2], acc[t][3]);
            *(uint2*)(OutB + (size_t)rw * 128 + t * 16 + q * 4) = o;
        }
    }
}

// ---------------------------------------------------------------------------
// fused_layer (swapped, 8-wave, node order, bf16 residual stream):
// GEMM1(Dm^T @ agg^T)+LN+relu -> GEMM2(W2 @ h^T)+res+LN ->
// [GEMM3(Sn^T @ x'^T) unless LAST].
// FIRST: residual = x0[rw] fp32.  !FIRST: residual = xpIn[rw] bf16.
// non-LAST stores x' bf16 (Pl/Ph words) to xpOut[rw]; LAST adds x0[rw] and
// writes final fp32 out[rw].
// ---------------------------------------------------------------------------

template <bool LAST, bool FIRST>
__global__ __launch_bounds__(512, 4) void fused_layer(
    const unsigned short* __restrict__ agg, const unsigned short* __restrict__ DmAll,
    const unsigned short* __restrict__ W2b, const unsigned short* __restrict__ SnAll,
    const int* __restrict__ blist, const int* __restrict__ boff,
    const int* __restrict__ tileOff, const float* __restrict__ dnorm,
    const float* __restrict__ b1v, const float* __restrict__ g1v,
    const float* __restrict__ e1v, const float* __restrict__ b2v,
    const float* __restrict__ g2v, const float* __restrict__ e2v,
    const float* __restrict__ rs_ptr, const float* __restrict__ x0n,
    const unsigned short* __restrict__ xpIn, unsigned short* __restrict__ xpOut,
    float* __restrict__ OutF, unsigned short* __restrict__ OutXt) {
    __shared__ unsigned short sB[128 * 128];  // 32 KiB (Dm -> W2 -> Sn)

    int tid = threadIdx.x, b = blockIdx.x;
    if (b >= tileOff[P_]) return;
    int pp = 0;
    while (pp < P_ - 1 && b >= tileOff[pp + 1]) ++pp;
    int tb = b - tileOff[pp];
    int cnt = boff[pp + 1] - boff[pp];
    int nrows = min(TM, cnt - tb * TM);
    int rowbase = boff[pp] + tb * TM;

    int lane = tid & 63, wave = tid >> 6;
    int n = lane & 15, q = lane >> 4;
    int rr = wave * 16 + n;
    int rw = (rr < nrows) ? blist[rowbase + rr] : -1;
    size_t grow = (rw >= 0) ? (size_t)rw : (size_t)N_;
    int s0 = n + ((q & 1) << 5), s1 = s0 + 16;  // exchange partners (q-group)
    bool hi = q >= 2;

    stage_B_async(DmAll + (size_t)pp * (D_ * D_), sB, wave, lane);
    bf16x8 bg[4];
#pragma unroll
    for (int kc = 0; kc < 4; ++kc)
        bg[kc] = *(const bf16x8*)(agg + grow * 128 + kc * 32 + q * 8);
    float dn = (rw >= 0) ? dnorm[rw] : 1.f;
    __syncthreads();  // #1: sB(Dm) + bg ready

    // ---- GEMM1: out1^T = Dm^T @ agg^T  (lane holds row rw, d=16t+4q+r) ----
    f32x4 acc[8];
#pragma unroll
    for (int t = 0; t < 8; ++t) acc[t] = (f32x4){0.f, 0.f, 0.f, 0.f};
#pragma unroll
    for (int kc = 0; kc < 4; ++kc) {
#pragma unroll
        for (int t = 0; t < 8; ++t) {
            int cs = ((((kc << 2) + q) ^ n) << 3);
            bf16x8 af = *(const bf16x8*)(sB + (t * 16 + n) * 128 + cs);
            acc[t] = __builtin_amdgcn_mfma_f32_16x16x32_bf16(af, bg[kc], acc[t], 0, 0, 0);
        }
    }

    // ---- LN1 + relu -> h (packed bf16 pairs Pl/Ph) ----
    unsigned Pl[8], Ph[8];
    {
        float rs1 = 0.f, rs2 = 0.f;
#pragma unroll
        for (int t = 0; t < 8; ++t) {
            float4 bb = *(const float4*)(b1v + t * 16 + q * 4);
#pragma unroll
            for (int r = 0; r < 4; ++r) {
                float v = dn * acc[t][r] + (&bb.x)[r];
                acc[t][r] = v;
                rs1 += v;
                rs2 += v * v;
            }
        }
        rs1 += __shfl_xor(rs1, 16, 64);
        rs1 += __shfl_xor(rs1, 32, 64);
        rs2 += __shfl_xor(rs2, 16, 64);
        rs2 += __shfl_xor(rs2, 32, 64);
        float mm = rs1 * (1.f / 128.f);
        float rv = rsqrtf(rs2 * (1.f / 128.f) - mm * mm + EPS_);
#pragma unroll
        for (int t = 0; t < 8; ++t) {
            float4 gg = *(const float4*)(g1v + t * 16 + q * 4);
            float4 ee = *(const float4*)(e1v + t * 16 + q * 4);
            float h0 = fmaxf((acc[t][0] - mm) * rv * gg.x + ee.x, 0.f);
            float h1 = fmaxf((acc[t][1] - mm) * rv * gg.y + ee.y, 0.f);
            float h2 = fmaxf((acc[t][2] - mm) * rv * gg.z + ee.z, 0.f);
            float h3 = fmaxf((acc[t][3] - mm) * rv * gg.w + ee.w, 0.f);
            Pl[t] = pack2bf(h0, h1);
            Ph[t] = pack2bf(h2, h3);
        }
    }

    __syncthreads();                     // #2: sB(Dm) free
    stage_B_async(W2b, sB, wave, lane);  // async; overlapped by exchange
    bf16x8 h2[4];
#pragma unroll
    for (int kc = 0; kc < 4; ++kc) XCH_FRAG(h2[kc], Pl, Ph, kc)
    __syncthreads();  // #3: sB(W2) ready

    // ---- GEMM2: out2^T = W2 @ h^T ----
#pragma unroll
    for (int t = 0; t < 8; ++t) acc[t] = (f32x4){0.f, 0.f, 0.f, 0.f};
#pragma unroll
    for (int kc = 0; kc < 4; ++kc) {
#pragma unroll
        for (int t = 0; t < 8; ++t) {
            int cs = ((((kc << 2) + q) ^ n) << 3);
            bf16x8 af = *(const bf16x8*)(sB + (t * 16 + n) * 128 + cs);
            acc[t] = __builtin_amdgcn_mfma_f32_16x16x32_bf16(af, h2[kc], acc[t], 0, 0, 0);
        }
    }

    // ---- residual (loaded at use point; TLP hides it) + LN2 -> x' ----
    float rsc = rs_ptr[0];
    {
        float xr4[8][4];
        if constexpr (FIRST) {
#pragma unroll
            for (int t = 0; t < 8; ++t) {
                if (rw >= 0) {
                    float4 v = *(const float4*)(x0n + (size_t)rw * 128 + t * 16 + q * 4);
                    xr4[t][0] = v.x; xr4[t][1] = v.y; xr4[t][2] = v.z; xr4[t][3] = v.w;
                } else {
                    xr4[t][0] = xr4[t][1] = xr4[t][2] = xr4[t][3] = 0.f;
                }
            }
        } else {
#pragma unroll
            for (int t = 0; t < 8; ++t) {
                if (rw >= 0) {
                    uint2 u = *(const uint2*)(xpIn + (size_t)rw * 128 + t * 16 + q * 4);
                    xr4[t][0] = bflo(u.x); xr4[t][1] = bfhi(u.x);
                    xr4[t][2] = bflo(u.y); xr4[t][3] = bfhi(u.y);
                } else {
                    xr4[t][0] = xr4[t][1] = xr4[t][2] = xr4[t][3] = 0.f;
                }
            }
        }
        float rs1 = 0.f, rs2 = 0.f;
#pragma unroll
        for (int t = 0; t < 8; ++t) {
            float4 bb = *(const float4*)(b2v + t * 16 + q * 4);
#pragma unroll
            for (int r = 0; r < 4; ++r) {
                float v = rsc * (acc[t][r] + (&bb.x)[r]) + xr4[t][r];
                acc[t][r] = v;
                rs1 += v;
                rs2 += v * v;
            }
        }
        rs1 += __shfl_xor(rs1, 16, 64);
        rs1 += __shfl_xor(rs1, 32, 64);
        rs2 += __shfl_xor(rs2, 16, 64);
        rs2 += __shfl_xor(rs2, 32, 64);
        float mm = rs1 * (1.f / 128.f);
        float rv = rsqrtf(rs2 * (1.f / 128.f) - mm * mm + EPS_);
        if constexpr (LAST) {
#pragma unroll
            for (int t = 0; t < 8; ++t) {
                float4 gg = *(const float4*)(g2v + t * 16 + q * 4);
                float4 ee = *(const float4*)(e2v + t * 16 + q * 4);
                if (rw >= 0) {
                    float4 xa = *(const float4*)(x0n + (size_t)rw * 128 + t * 16 + q * 4);
                    float4 o;
                    o.x = (acc[t][0] - mm) * rv * gg.x + ee.x + xa.x;
                    o.y = (acc[t][1] - mm) * rv * gg.y + ee.y + xa.y;
                    o.z = (acc[t][2] - mm) * rv * gg.z + ee.z + xa.z;
                    o.w = (acc[t][3] - mm) * rv * gg.w + ee.w + xa.w;
                    *(float4*)(OutF + (size_t)rw * 128 + t * 16 + q * 4) = o;
                }
            }
        } else {
#pragma unroll
            for (int t = 0; t < 8; ++t) {
                float4 gg = *(const float4*)(g2v + t * 16 + q * 4);
                float4 ee = *(const float4*)(e2v + t * 16 + q * 4);
                float o0 = (acc[t][0] - mm) * rv * gg.x + ee.x;
                float o1 = (acc[t][1] - mm) * rv * gg.y + ee.y;
                float o2 = (acc[t][2] - mm) * rv * gg.z + ee.z;
                float o3 = (acc[t][3] - mm) * rv * gg.w + ee.w;
                Pl[t] = pack2bf(o0, o1);
                Ph[t] = pack2bf(o2, o3);
            }
        }
    }

    if constexpr (!LAST) {
        __syncthreads();  // #4: sB(W2) free
        stage_B_async(SnAll + (size_t)pp * (D_ * D_), sB, wave, lane);
        bf16x8 x2[4];
#pragma unroll
        for (int kc = 0; kc < 4; ++kc) XCH_FRAG(x2[kc], Pl, Ph, kc)
        __syncthreads();  // #5: sB(Sn) ready

        // ---- GEMM3: xt^T = Sn^T @ x'^T ----
#pragma unroll
        for (int t = 0; t < 8; ++t) acc[t] = (f32x4){0.f, 0.f, 0.f, 0.f};
#pragma unroll
        for (int kc = 0; kc < 4; ++kc) {
#pragma unroll
            for (int t = 0; t < 8; ++t) {
                int cs = ((((kc << 2) + q) ^ n) << 3);
                bf16x8 af = *(const bf16x8*)(sB + (t * 16 + n) * 128 + cs);
                acc[t] = __builtin_amdgcn_mfma_f32_16x16x32_bf16(af, x2[kc], acc[t], 0, 0, 0);
            }
        }
        if (rw >= 0) {
#pragma unroll
            for (int t = 0; t < 8; ++t) {
                uint2 o;
                o.x = pack2bf(acc[t][0], acc[t][1]);
                o.y = pack2bf(acc[t][2], acc[t][3]);
                *(uint2*)(OutXt + (size_t)rw * 128 + t * 16 + q * 4) = o;
            }
            // bf16 x' residual store — Pl/Ph already packed (12.8MB vs 25.6MB)
#pragma unroll
            for (int t = 0; t < 8; ++t) {
                uint2 h;
                h.x = Pl[t];
                h.y = Ph[t];
                *(uint2*)(xpOut + (size_t)rw * 128 + t * 16 + q * 4) = h;
            }
        }
    }
}

// ---------------------------------------------------------------------------
// Host launch
// ---------------------------------------------------------------------------

extern "C" void kernel_launch(void* const* d_in, const int* in_sizes, int n_in,
                              void* d_out, int out_size, void* d_ws, size_t ws_size,
                              hipStream_t stream) {
    const float* x0 = (const float*)d_in[0];
    const int* ei = (const int*)d_in[1];
    const int* ring = (const int*)d_in[2];
    const float* Wr = (const float*)d_in[3];
    const float* S = (const float*)d_in[4];
    const float* dS = (const float*)d_in[5];
    const float* R = (const float*)d_in[6];
    const float* dR = (const float*)d_in[7];
    const float* rsc = (const float*)d_in[8];
    const float* W1 = (const float*)d_in[9];
    const float* b1 = (const float*)d_in[10];
    const float* lng = (const float*)d_in[11];
    const float* lnb = (const float*)d_in[12];
    const float* W2 = (const float*)d_in[13];
    const float* b2 = (const float*)d_in[14];
    const float* ng = (const float*)d_in[15];
    const float* nb = (const float*)d_in[16];
    float* out = (float*)d_out;

    char* w = (char*)d_ws;
    auto alloc = [&](size_t bytes) {
        char* p = w;
        w += (bytes + 15) & ~(size_t)15;
        return p;
    };
    unsigned short* xb = (unsigned short*)alloc((size_t)(N_ + 1) * D_ * 2);    // bf16 x0 (+zero row)
    unsigned short* bufAb = (unsigned short*)alloc((size_t)(N_ + 1) * D_ * 2); // xt (+zero row)
    unsigned short* bufBb = (unsigned short*)alloc((size_t)(N_ + 1) * D_ * 2); // agg (+zero row)
    unsigned short* xpb = (unsigned short*)alloc((size_t)(N_ + 1) * D_ * 2);   // bf16 x' residual
    unsigned short* Sb = (unsigned short*)alloc((size_t)L_ * P_ * D_ * D_ * 2);
    unsigned short* Dmb = (unsigned short*)alloc((size_t)L_ * P_ * D_ * D_ * 2);
    unsigned short* W2b = (unsigned short*)alloc((size_t)L_ * D_ * D_ * 2);
    unsigned short* Arh = (unsigned short*)alloc((size_t)MAT * 16384 * 2);
    unsigned short* Arl = (unsigned short*)alloc((size_t)MAT * 16384 * 2);
    unsigned short* W1h = (unsigned short*)alloc((size_t)3 * 16384 * 2);
    unsigned short* W1l = (unsigned short*)alloc((size_t)3 * 16384 * 2);
    unsigned short* Wrth = (unsigned short*)alloc((size_t)3 * 16384 * 2);
    unsigned short* Wrtl = (unsigned short*)alloc((size_t)3 * 16384 * 2);
    unsigned short* T1th = (unsigned short*)alloc((size_t)MAT * 16384 * 2);
    unsigned short* T1tl = (unsigned short*)alloc((size_t)MAT * 16384 * 2);
    float* dnorm = (float*)alloc((size_t)N_ * 4);
    int* histG = (int*)alloc((size_t)HTOT * 4);
    unsigned* bufT = (unsigned*)alloc((size_t)E_ * 4);
    unsigned char* bufS8 = (unsigned char*)alloc((size_t)E_);
    unsigned short* eSrc = (unsigned short*)alloc((size_t)E_ * 2);
    int* offT = (int*)alloc((size_t)(N_ + 1) * 4);
    int* pol = (int*)alloc((size_t)N_ * 4);
    int* boff = (int*)alloc((size_t)(P_ + 1) * 4);
    int* tileOff = (int*)alloc((size_t)(P_ + 1) * 4);
    int* blist = (int*)alloc((size_t)N_ * 4);
    int* blkSum = (int*)alloc((size_t)NSB * 4);
    int* blkOff = (int*)alloc((size_t)NSB * 4);
    int* bcnt = (int*)alloc((size_t)2 * P_ * 4);  // zeroed region: bcnt + bcur
    int* bcur = bcnt + P_;

    hipMemsetAsync(bcnt, 0, (size_t)2 * P_ * 4, stream);

    const int BTILES = N_ / TM + P_;  // 399, upper bound on bucketed tiles

    setup_nk<<<NBK, 256, 0, stream>>>(ring, pol, bcnt, ei, histG);
    scanH1<<<NSB, 1024, 0, stream>>>(histG, blkSum);
    scanH2<<<1, 64, 0, stream>>>(blkSum, blkOff, offT, bcnt, boff, tileOff);
    scanH3<<<NSB, 1024, 0, stream>>>(histG, blkOff);
    scatterTS<<<NBK, 256, 0, stream>>>(ei, histG, bufT, bufS8);
    finalize3<<<3 * NBUK, 256, 0, stream>>>(bufT, bufS8, histG, offT, eSrc, dnorm,
                                            pol, boff, bcur, blist);
    prep_all<<<GPREP, 256, 0, stream>>>(x0, xb, bufAb, bufBb, S, dS, Sb, W2, W2b,
                                        R, dR, W1, Wr, Arh, Arl, W1h, W1l, Wrth, Wrtl);
    // T1t[mat][k][i] = sum_j W1[l][k][j] * (R+dR)[mat][i][j]
    small_mfma<false, true, true><<<2 * MAT, 256, 0, stream>>>(
        W1h, W1l, Arh, Arl, T1th, T1tl);
    // Dmb[mat][k][d] = sum_i T1t[mat][k][i] * Wr^T[l][d][i]
    small_mfma<true, false, false><<<2 * MAT, 256, 0, stream>>>(
        T1th, T1tl, Wrth, Wrtl, Dmb, nullptr);

    // layer 0 send-transform: xt0 = x0 @ (S+dS)[0][pol]
    gemm_xt0<<<BTILES, 512, 0, stream>>>(xb, Sb, bufAb, blist, boff, tileOff);

    for (int l = 0; l < L_; ++l) {
        const size_t lPDD = (size_t)l * P_ * D_ * D_;
        const size_t lDD = (size_t)l * D_ * D_;
        const size_t lD = (size_t)l * D_;
        aggregate_bf<<<N_ / 4, 256, 0, stream>>>(bufAb, offT, eSrc, bufBb);
        if (l == 0) {
            fused_layer<false, true><<<BTILES, 512, 0, stream>>>(
                bufBb, Dmb + lPDD, W2b + lDD, Sb + lPDD + (size_t)P_ * D_ * D_,
                blist, boff, tileOff, dnorm,
                b1 + lD, lng + lD, lnb + lD, b2 + lD, ng + lD, nb + lD,
                rsc + l, x0, nullptr, xpb, nullptr, bufAb);
        } else if (l < L_ - 1) {
            fused_layer<false, false><<<BTILES, 512, 0, stream>>>(
                bufBb, Dmb + lPDD, W2b + lDD, Sb + lPDD + (size_t)P_ * D_ * D_,
                blist, boff, tileOff, dnorm,
                b1 + lD, lng + lD, lnb + lD, b2 + lD, ng + lD, nb + lD,
                rsc + l, nullptr, xpb, xpb, nullptr, bufAb);
        } else {
            fused_layer<true, false><<<BTILES, 512, 0, stream>>>(
                bufBb, Dmb + lPDD, W2b + lDD, nullptr,
                blist, boff, tileOff, dnorm,
                b1 + lD, lng + lD, lnb + lD, b2 + lD, ng + lD, nb + lD,
                rsc + l, x0, xpb, nullptr, out, nullptr);
        }
    }
}

// Round 9
// 357.696 us; speedup vs baseline: 1.0411x; 1.0066x over previous
//
#include <hip/hip_runtime.h>
#include <hip/hip_bf16.h>

// Problem constants
constexpr int N_ = 50000;
constexpr int D_ = 128;
constexpr int E_ = 800000;
constexpr int P_ = 9;
constexpr int L_ = 3;
constexpr float EPS_ = 1e-5f;

constexpr int TM = 128;   // rows per GEMM block (8 waves x 16 rows)
constexpr int CHUNK = 4096;                    // edges per hist/scatter block
constexpr int NBK = (E_ + CHUNK - 1) / CHUNK;  // 196 edge chunks
constexpr int NBUK = 196;                      // node buckets (50000>>8 = 195 max)
constexpr int HHALF = 256 * NBK;               // 50176 (per-half hist size)
constexpr int HTOT = 2 * HHALF;                // 100352 = 98 * 1024 exactly
constexpr int NSB = HTOT / 1024;               // 98 scan blocks
constexpr int MAT = L_ * P_;                   // 27 small matrices

typedef short bf16x8 __attribute__((ext_vector_type(8)));
typedef float f32x4 __attribute__((ext_vector_type(4)));

// async 16B global->LDS copy; lds base must be wave-uniform, data lands at
// base + lane*16  [guide §5, m97]
#define GLD16(gp, lp)                                                        \
    __builtin_amdgcn_global_load_lds(                                        \
        (const __attribute__((address_space(1))) unsigned int*)(gp),         \
        (__attribute__((address_space(3))) unsigned int*)(lp), 16, 0, 0)

__device__ inline unsigned short f2bf(float f) {
    __hip_bfloat16 h = __float2bfloat16(f);
    return *reinterpret_cast<unsigned short*>(&h);
}
__device__ inline float bflo(unsigned u) { return __uint_as_float(u << 16); }
__device__ inline float bfhi(unsigned u) { return __uint_as_float(u & 0xffff0000u); }
__device__ inline float bf2f(unsigned short h) {
    return __uint_as_float((unsigned)h << 16);
}
__device__ inline unsigned pack2bf(float a, float b) {
    return (unsigned)f2bf(a) | ((unsigned)f2bf(b) << 16);
}

// ---------------------------------------------------------------------------
// setup_nk: node polarity init + edge histograms (merged)
// ---------------------------------------------------------------------------

__global__ __launch_bounds__(256) void setup_nk(const int* __restrict__ ring,
                                                int* __restrict__ pol,
                                                int* __restrict__ bcnt,
                                                const int* __restrict__ ei,
                                                int* __restrict__ histG) {
    __shared__ int h[P_];
    __shared__ int hT[256], hS[256];
    int blk = blockIdx.x, tid = threadIdx.x;
    if (tid < P_) h[tid] = 0;
    hT[tid] = 0;
    hS[tid] = 0;
    __syncthreads();
    int n = blk * 256 + tid;
    if (n < N_) {
        int p = ring[n] % P_;
        pol[n] = p;
        atomicAdd(&h[p], 1);
    }
    int base = blk * CHUNK;
#pragma unroll
    for (int i = 0; i < CHUNK / 256; ++i) {
        int e = base + tid + i * 256;
        if (e < E_) {
            atomicAdd(&hS[ei[e] >> 8], 1);
            atomicAdd(&hT[ei[E_ + e] >> 8], 1);
        }
    }
    __syncthreads();
    if (tid < P_ && h[tid] > 0) atomicAdd(&bcnt[tid], h[tid]);
    histG[tid * NBK + blk] = hT[tid];
    histG[HHALF + tid * NBK + blk] = hS[tid];
}

// ---------------------------------------------------------------------------
// scanH1: per-1024-block exclusive scan of histG + blkSum. Global offsets are
// folded in by CONSUMERS (scatterTS / finprep finalize roles) via an LDS scan
// of blkSum — scanH2 (1-thread kernel) and scanH3 (full extra pass) deleted.
// ---------------------------------------------------------------------------

__global__ __launch_bounds__(1024) void scanH1(int* __restrict__ a,
                                               int* __restrict__ blkSum) {
    __shared__ int wsum[16];
    int tid = threadIdx.x, lane = tid & 63, wid = tid >> 6;
    int idx = blockIdx.x * 1024 + tid;
    int v = a[idx];
    int inc = v;
#pragma unroll
    for (int o = 1; o < 64; o <<= 1) {
        int t = __shfl_up(inc, o, 64);
        if (lane >= o) inc += t;
    }
    if (lane == 63) wsum[wid] = inc;
    __syncthreads();
    if (tid < 16) {
        int s = wsum[tid];
#pragma unroll
        for (int o = 1; o < 16; o <<= 1) {
            int t = __shfl_up(s, o, 64);
            if (tid >= o) s += t;
        }
        wsum[tid] = s;
    }
    __syncthreads();
    int wexcl = (wid == 0) ? 0 : wsum[wid - 1];
    a[idx] = wexcl + inc - v;
    if (tid == 1023) blkSum[blockIdx.x] = wsum[15];
}

// ---------------------------------------------------------------------------
// scatterTS: edge scatter with self-computed global scan offsets (bOff from
// blkSum, serial LDS scan by tid 0 — ~100 adds, off critical path).
// ---------------------------------------------------------------------------

__global__ __launch_bounds__(256) void scatterTS(const int* __restrict__ ei,
                                                 const int* __restrict__ histG,
                                                 const int* __restrict__ blkSum,
                                                 unsigned* __restrict__ bufT,
                                                 unsigned char* __restrict__ bufS8) {
    __shared__ int ldsT[256], ldsS[256];
    __shared__ int bOff[NSB];
    int blk = blockIdx.x, tid = threadIdx.x;
    if (tid < NSB) bOff[tid] = blkSum[tid];
    __syncthreads();
    if (tid == 0) {
        int run = 0;
        for (int i = 0; i < NSB; ++i) {
            int t = bOff[i];
            bOff[i] = run;
            run += t;
        }
    }
    __syncthreads();
    int i1 = tid * NBK + blk;
    int i2 = HHALF + i1;
    ldsT[tid] = histG[i1] + bOff[i1 >> 10];
    ldsS[tid] = histG[i2] + bOff[i2 >> 10] - E_;
    __syncthreads();
    int base = blk * CHUNK;
#pragma unroll
    for (int i = 0; i < CHUNK / 256; ++i) {
        int e = base + tid + i * 256;
        if (e < E_) {
            int s = ei[e], t = ei[E_ + e];
            int pT = atomicAdd(&ldsT[t >> 8], 1);
            bufT[pT] = ((unsigned)t << 16) | (unsigned)s;
            int pS = atomicAdd(&ldsS[s >> 8], 1);
            bufS8[pS] = (unsigned char)(s & 255);
        }
    }
}

// ---------------------------------------------------------------------------
// finprep: prep_all roles (conv4 | zero | prep_S | prep_W2 | prep_split)
// MERGED with finalizeT | finalizeS | bucket_fill. One launch instead of two;
// finalize roles self-compute global scan offsets (bOff) and bucket offsets
// (boff from bcnt); bucket_fill block 0 publishes boff/tileOff/offT[N_].
// ---------------------------------------------------------------------------

constexpr int GCONV = N_ * D_ / 4 / 256;       // 6250
constexpr int GS = L_ * P_ * D_ * D_ / 256;    // 1728
constexpr int GW2 = L_ * D_ * D_ / 256;        // 192
constexpr int GSPL = (MAT + 6) * 16384 / 256;  // 2112
constexpr int GPREP = GCONV + 1 + GS + GW2 + GSPL;
constexpr int GFIN = GPREP + 3 * NBUK;

__global__ __launch_bounds__(256) void finprep(
    const float* __restrict__ x, unsigned short* __restrict__ xb,
    unsigned short* __restrict__ bufAb, unsigned short* __restrict__ bufBb,
    const float* __restrict__ S, const float* __restrict__ dS,
    unsigned short* __restrict__ Sb,
    const float* __restrict__ W2, unsigned short* __restrict__ W2b,
    const float* __restrict__ R, const float* __restrict__ dR,
    const float* __restrict__ W1, const float* __restrict__ Wr,
    unsigned short* __restrict__ Arh, unsigned short* __restrict__ Arl,
    unsigned short* __restrict__ W1h, unsigned short* __restrict__ W1l,
    unsigned short* __restrict__ Wrth, unsigned short* __restrict__ Wrtl,
    const unsigned* __restrict__ bufT, const unsigned char* __restrict__ bufS8,
    const int* __restrict__ histG, const int* __restrict__ blkSum,
    int* __restrict__ offT, unsigned short* __restrict__ eSrc,
    float* __restrict__ dnorm, const int* __restrict__ pol,
    const int* __restrict__ bcnt, int* __restrict__ bcur,
    int* __restrict__ blist, int* __restrict__ boffG, int* __restrict__ tileOffG) {
    __shared__ int s0[256];
    __shared__ int s1[256];
    __shared__ int bOffs[NSB];
    __shared__ int boffL[P_ + 1];
    int b = blockIdx.x, tid = threadIdx.x;

    if (b < GCONV) {
        int i = b * 256 + tid;
        float4 v = ((const float4*)x)[i];
        ushort4 o;
        o.x = f2bf(v.x); o.y = f2bf(v.y); o.z = f2bf(v.z); o.w = f2bf(v.w);
        ((ushort4*)xb)[i] = o;
    } else if (b < GCONV + 1) {
        if (tid < 64) {
            ((unsigned*)(xb + (size_t)N_ * D_))[tid] = 0;
            ((unsigned*)(bufAb + (size_t)N_ * D_))[tid] = 0;
            ((unsigned*)(bufBb + (size_t)N_ * D_))[tid] = 0;
        }
    } else if (b < GCONV + 1 + GS) {
        int idx = (b - GCONV - 1) * 256 + tid;
        int base = idx / (D_ * D_);
        int rem = idx % (D_ * D_);
        int c = rem / D_, d = rem % D_;
        size_t in = (size_t)base * D_ * D_ + (size_t)d * D_ + c;
        Sb[idx] = f2bf(S[in] + dS[in]);
    } else if (b < GCONV + 1 + GS + GW2) {
        int idx = (b - GCONV - 1 - GS) * 256 + tid;
        W2b[idx] = f2bf(W2[idx]);
    } else if (b < GPREP) {
        constexpr int SZ1 = MAT * 16384;
        constexpr int SZ2 = SZ1 + 3 * 16384;
        int idx = (b - GCONV - 1 - GS - GW2) * 256 + tid;
        float v;
        unsigned short* oh;
        unsigned short* ol;
        int j;
        if (idx < SZ1) {
            v = R[idx] + dR[idx];
            oh = Arh; ol = Arl; j = idx;
        } else if (idx < SZ2) {
            j = idx - SZ1;
            v = W1[j];
            oh = W1h; ol = W1l;
        } else {
            j = idx - SZ2;
            int l = j >> 14, rem = j & 16383;
            int d = rem >> 7, i = rem & 127;
            v = Wr[(l << 14) + i * 128 + d];
            oh = Wrth; ol = Wrtl;
        }
        unsigned short h = f2bf(v);
        oh[j] = h;
        ol[j] = f2bf(v - bf2f(h));
    } else {
        int bb = b - GPREP;
        if (bb < NBUK) {
            // ---- finalizeT: per-node offsets + eSrc fill ----
            int bk = bb;
            if (tid < NSB) bOffs[tid] = blkSum[tid];
            s0[tid] = 0;
            __syncthreads();
            if (tid == 0) {
                int run = 0;
                for (int i = 0; i < NSB; ++i) {
                    int t = bOffs[i];
                    bOffs[i] = run;
                    run += t;
                }
            }
            __syncthreads();
            int i0 = bk * NBK, i1 = (bk + 1) * NBK;
            int start = histG[i0] + bOffs[i0 >> 10];
            int end = histG[i1] + bOffs[i1 >> 10];
            for (int i = start + tid; i < end; i += 256)
                atomicAdd(&s0[(bufT[i] >> 16) & 255], 1);
            __syncthreads();
            if (tid < 64) {
                int b0 = 4 * tid;
                int v0 = s0[b0], v1 = s0[b0 + 1], v2 = s0[b0 + 2], v3 = s0[b0 + 3];
                int lsum = v0 + v1 + v2 + v3;
                int inc = lsum;
#pragma unroll
                for (int o = 1; o < 64; o <<= 1) {
                    int t = __shfl_up(inc, o, 64);
                    if (tid >= o) inc += t;
                }
                int excl = inc - lsum;
                s1[b0] = excl;
                s1[b0 + 1] = excl + v0;
                s1[b0 + 2] = excl + v0 + v1;
                s1[b0 + 3] = excl + v0 + v1 + v2;
            }
            __syncthreads();
            int node = (bk << 8) + tid;
            if (node < N_) offT[node] = start + s1[tid];
            __syncthreads();
            for (int i = start + tid; i < end; i += 256) {
                unsigned pk = bufT[i];
                int pos = start + atomicAdd(&s1[(pk >> 16) & 255], 1);
                eSrc[pos] = (unsigned short)(pk & 0xFFFF);
            }
        } else if (bb < 2 * NBUK) {
            // ---- finalizeS: degree counts -> dnorm ----
            int bk = bb - NBUK;
            if (tid < NSB) bOffs[tid] = blkSum[tid];
            s0[tid] = 0;
            __syncthreads();
            if (tid == 0) {
                int run = 0;
                for (int i = 0; i < NSB; ++i) {
                    int t = bOffs[i];
                    bOffs[i] = run;
                    run += t;
                }
            }
            __syncthreads();
            int i0 = HHALF + bk * NBK, i1 = HHALF + (bk + 1) * NBK;
            int start = histG[i0] + bOffs[i0 >> 10] - E_;
            int end = histG[i1] + bOffs[i1 >> 10] - E_;
            for (int i = start + tid; i < end; i += 256) atomicAdd(&s0[bufS8[i]], 1);
            __syncthreads();
            int node = (bk << 8) + tid;
            if (node < N_) {
                int dg = s0[tid];
                dnorm[node] = 1.f / (float)(dg > 1 ? dg : 1);
            }
        } else {
            // ---- bucket_fill: blist + publish boff/tileOff/offT[N_] ----
            int bk = bb - 2 * NBUK;
            if (tid == 0) {
                int run = 0;
                for (int p = 0; p < P_; ++p) {
                    boffL[p] = run;
                    run += bcnt[p];
                }
                boffL[P_] = run;
            }
            if (tid < P_) s0[tid] = 0;
            __syncthreads();
            if (bk == 0 && tid == 0) {
                offT[N_] = E_;
                int runT = 0;
                for (int p = 0; p < P_; ++p) {
                    boffG[p] = boffL[p];
                    tileOffG[p] = runT;
                    runT += (bcnt[p] + TM - 1) / TM;
                }
                boffG[P_] = boffL[P_];
                tileOffG[P_] = runT;
            }
            int n = bk * 256 + tid;
            int p = 0, loc = 0;
            bool act = (n < N_);
            if (act) {
                p = pol[n];
                loc = atomicAdd(&s0[p], 1);
            }
            __syncthreads();
            if (tid < P_ && s0[tid] > 0) s1[tid] = atomicAdd(&bcur[tid], s0[tid]);
            __syncthreads();
            if (act) blist[boffL[p] + s1[p] + loc] = n;
        }
    }
}

// ---------------------------------------------------------------------------
// Batched small MFMA GEMM (fp32-equivalent via 2-term bf16 split)
// ---------------------------------------------------------------------------

template <bool APM, bool BPM, bool OUT_SPLIT>
__global__ __launch_bounds__(256) void small_mfma(
    const unsigned short* __restrict__ Ah, const unsigned short* __restrict__ Al,
    const unsigned short* __restrict__ Bh, const unsigned short* __restrict__ Bl,
    unsigned short* __restrict__ Oh, unsigned short* __restrict__ Ol) {
    __shared__ unsigned short stg[(OUT_SPLIT ? 2 : 1) * 64 * 136];
    int tid = threadIdx.x, b = blockIdx.x;
    int mat = b >> 1, rb = b & 1;
    int l = mat / P_;
    size_t aoff = (size_t)(APM ? mat : l) * 16384 + (size_t)rb * 8192;
    size_t boff = (size_t)(BPM ? mat : l) * 16384;
    const unsigned short* ahp = Ah + aoff;
    const unsigned short* alp = Al + aoff;
    const unsigned short* bhp = Bh + boff;
    const unsigned short* blp = Bl + boff;

    int lane = tid & 63, wave = tid >> 6;
    int n = lane & 15, q = lane >> 4;
    int wr = wave * 16;

    f32x4 acc[8];
#pragma unroll
    for (int t = 0; t < 8; ++t) acc[t] = (f32x4){0.f, 0.f, 0.f, 0.f};

    int arow = (wr + n) * 128;
#pragma unroll
    for (int kc = 0; kc < 4; ++kc) {
        int ko = kc * 32 + q * 8;
        bf16x8 avh = *(const bf16x8*)(ahp + arow + ko);
        bf16x8 avl = *(const bf16x8*)(alp + arow + ko);
#pragma unroll
        for (int t = 0; t < 8; ++t) {
            int brow = (t * 16 + n) * 128;
            bf16x8 bvh = *(const bf16x8*)(bhp + brow + ko);
            bf16x8 bvl = *(const bf16x8*)(blp + brow + ko);
            acc[t] = __builtin_amdgcn_mfma_f32_16x16x32_bf16(avh, bvh, acc[t], 0, 0, 0);
            acc[t] = __builtin_amdgcn_mfma_f32_16x16x32_bf16(avh, bvl, acc[t], 0, 0, 0);
            acc[t] = __builtin_amdgcn_mfma_f32_16x16x32_bf16(avl, bvh, acc[t], 0, 0, 0);
        }
    }
#pragma unroll
    for (int t = 0; t < 8; ++t)
#pragma unroll
        for (int r = 0; r < 4; ++r) {
            int row = wr + q * 4 + r;
            float v = acc[t][r];
            unsigned short h = f2bf(v);
            stg[row * 136 + t * 16 + n] = h;
            if constexpr (OUT_SPLIT)
                stg[64 * 136 + row * 136 + t * 16 + n] = f2bf(v - bf2f(h));
        }
    __syncthreads();
    size_t obase = (size_t)mat * 16384 + (size_t)rb * 8192;
#pragma unroll
    for (int i = 0; i < 4; ++i) {
        int c = tid + i * 256;
        int r = c >> 4, off = c & 15;
        *(uint4*)(Oh + obase + r * 128 + off * 8) =
            *(const uint4*)(stg + r * 136 + off * 8);
        if constexpr (OUT_SPLIT)
            *(uint4*)(Ol + obase + r * 128 + off * 8) =
                *(const uint4*)(stg + 64 * 136 + r * 136 + off * 8);
    }
}

// ---------------------------------------------------------------------------
// CSR aggregation: 4 dwordx4 gathers in flight, lane-preloaded indices
// ---------------------------------------------------------------------------

__device__ inline void accum_row(float* acc, uint4 r) {
    acc[0] += bflo(r.x); acc[1] += bfhi(r.x);
    acc[2] += bflo(r.y); acc[3] += bfhi(r.y);
    acc[4] += bflo(r.z); acc[5] += bfhi(r.z);
    acc[6] += bflo(r.w); acc[7] += bfhi(r.w);
}

__global__ __launch_bounds__(256) void aggregate_bf(const unsigned short* __restrict__ xt,
                                                    const int* __restrict__ offT,
                                                    const unsigned short* __restrict__ eSrc,
                                                    unsigned short* __restrict__ agg) {
    int nd = blockIdx.x * 4 + (threadIdx.x >> 6);
    if (nd >= N_) return;
    int l = threadIdx.x & 63;
    int g = l >> 4, c16 = l & 15;
    int beg = offT[nd], end = offT[nd + 1];

    float acc[8];
#pragma unroll
    for (int k = 0; k < 8; ++k) acc[k] = 0.f;

    for (int base = beg; base < end; base += 64) {
        int cnt = min(64, end - base);
        int idxv = (l < cnt) ? (int)eSrc[base + l] : 0;
        int steps = (cnt + 3) >> 2;
        int j = 0;
        for (; j + 3 < steps; j += 4) {
            int e0 = 4 * j + g, e1 = e0 + 4, e2 = e0 + 8, e3 = e0 + 12;
            int i0 = __shfl(idxv, e0, 64);
            int i1 = __shfl(idxv, e1, 64);
            int i2 = __shfl(idxv, e2, 64);
            int i3 = __shfl(idxv, e3, 64);
            int r0 = (e0 < cnt) ? i0 : N_;
            int r1 = (e1 < cnt) ? i1 : N_;
            int r2 = (e2 < cnt) ? i2 : N_;
            int r3 = (e3 < cnt) ? i3 : N_;
            uint4 v0 = ((const uint4*)(xt + (size_t)r0 * D_))[c16];
            uint4 v1 = ((const uint4*)(xt + (size_t)r1 * D_))[c16];
            uint4 v2 = ((const uint4*)(xt + (size_t)r2 * D_))[c16];
            uint4 v3 = ((const uint4*)(xt + (size_t)r3 * D_))[c16];
            accum_row(acc, v0);
            accum_row(acc, v1);
            accum_row(acc, v2);
            accum_row(acc, v3);
        }
        for (; j < steps; ++j) {
            int e0 = 4 * j + g;
            int i0 = __shfl(idxv, e0, 64);
            int r0 = (e0 < cnt) ? i0 : N_;
            uint4 v0 = ((const uint4*)(xt + (size_t)r0 * D_))[c16];
            accum_row(acc, v0);
        }
    }
#pragma unroll
    for (int k = 0; k < 8; ++k) {
        acc[k] += __shfl_xor(acc[k], 16, 64);
        acc[k] += __shfl_xor(acc[k], 32, 64);
    }
    if (g == 0) {
        uint4 o;
        o.x = (unsigned)f2bf(acc[0]) | ((unsigned)f2bf(acc[1]) << 16);
        o.y = (unsigned)f2bf(acc[2]) | ((unsigned)f2bf(acc[3]) << 16);
        o.z = (unsigned)f2bf(acc[4]) | ((unsigned)f2bf(acc[5]) << 16);
        o.w = (unsigned)f2bf(acc[6]) | ((unsigned)f2bf(acc[7]) << 16);
        ((uint4*)(agg + (size_t)nd * D_))[c16] = o;
    }
}

// ---------------------------------------------------------------------------
// Round 9 = R8 compute kernels (360.1us best) + serial-chain diet:
// scanH2/scanH3 deleted (offsets folded into consumers), prep+finalize merged.
// 15 -> 12 dispatches; zero arithmetic change (absmax must stay 0.0625).
// ---------------------------------------------------------------------------

// stage one 128x128 bf16 matrix into sB, async, 8 waves x 4 segs
__device__ inline void stage_B_async(const unsigned short* __restrict__ B,
                                     unsigned short* sB, int wave, int lane) {
    int rsub = lane >> 4, cl = lane & 15;
#pragma unroll
    for (int j = 0; j < 4; ++j) {
        int seg = wave * 4 + j;
        int row = seg * 4 + rsub;
        GLD16(B + row * 128 + ((cl ^ (row & 15)) << 3), sB + seg * 512);
    }
}

// build bf16x8 B-frag (dims 32kc+8q .. +7 of own row) from packed bf16 pairs
// Pl/Ph (Pl[t] = dims {16t+4q+0,1}, Ph[t] = {+2,+3}) via 4-lane exchange.
#define XCH_FRAG(dst, Pl, Ph, kc)                                            \
    {                                                                        \
        unsigned a0 = __shfl(Pl[2 * (kc)], s0, 64);                          \
        unsigned b0 = __shfl(Pl[2 * (kc) + 1], s0, 64);                      \
        unsigned a1 = __shfl(Ph[2 * (kc)], s0, 64);                          \
        unsigned b1 = __shfl(Ph[2 * (kc) + 1], s0, 64);                      \
        unsigned a2 = __shfl(Pl[2 * (kc)], s1, 64);                          \
        unsigned b2 = __shfl(Pl[2 * (kc) + 1], s1, 64);                      \
        unsigned a3 = __shfl(Ph[2 * (kc)], s1, 64);                          \
        unsigned b3 = __shfl(Ph[2 * (kc) + 1], s1, 64);                      \
        union { unsigned u[4]; bf16x8 v; } fu;                               \
        fu.u[0] = hi ? b0 : a0;                                              \
        fu.u[1] = hi ? b1 : a1;                                              \
        fu.u[2] = hi ? b2 : a2;                                              \
        fu.u[3] = hi ? b3 : a3;                                              \
        dst = fu.v;                                                          \
    }

// ---------------------------------------------------------------------------
// gemm_xt0: xt = xb @ Sb[0][pol], bucketed. Swapped form, 1 barrier, no sA.
// ---------------------------------------------------------------------------

__global__ __launch_bounds__(512, 4) void gemm_xt0(
    const unsigned short* __restrict__ A, const unsigned short* __restrict__ Bw,
    unsigned short* __restrict__ OutB, const int* __restrict__ blist,
    const int* __restrict__ boff, const int* __restrict__ tileOff) {
    __shared__ unsigned short sB[128 * 128];
    int tid = threadIdx.x, b = blockIdx.x;
    if (b >= tileOff[P_]) return;
    int pp = 0;
    while (pp < P_ - 1 && b >= tileOff[pp + 1]) ++pp;
    int tb = b - tileOff[pp];
    int cnt = boff[pp + 1] - boff[pp];
    int nrows = min(TM, cnt - tb * TM);
    int rowbase = boff[pp] + tb * TM;

    int lane = tid & 63, wave = tid >> 6;
    int n = lane & 15, q = lane >> 4;
    int rr = wave * 16 + n;
    int rw = (rr < nrows) ? blist[rowbase + rr] : -1;
    size_t grow = (rw >= 0) ? (size_t)rw : (size_t)N_;

    stage_B_async(Bw + (size_t)pp * (D_ * D_), sB, wave, lane);
    bf16x8 bg[4];
#pragma unroll
    for (int kc = 0; kc < 4; ++kc)
        bg[kc] = *(const bf16x8*)(A + grow * 128 + kc * 32 + q * 8);
    __syncthreads();  // drains stage + bg

    f32x4 acc[8];
#pragma unroll
    for (int t = 0; t < 8; ++t) acc[t] = (f32x4){0.f, 0.f, 0.f, 0.f};
#pragma unroll
    for (int kc = 0; kc < 4; ++kc) {
#pragma unroll
        for (int t = 0; t < 8; ++t) {
            int cs = ((((kc << 2) + q) ^ n) << 3);
            bf16x8 af = *(const bf16x8*)(sB + (t * 16 + n) * 128 + cs);
            acc[t] = __builtin_amdgcn_mfma_f32_16x16x32_bf16(af, bg[kc], acc[t], 0, 0, 0);
        }
    }
    if (rw >= 0) {
#pragma unroll
        for (int t = 0; t < 8; ++t) {
            uint2 o;
            o.x = pack2bf(acc[t][0], acc[t][1]);
            o.y = pack2bf(acc[t][2], acc[t][3]);
            *(uint2*)(OutB + (size_t)rw * 128 + t * 16 + q * 4) = o;
        }
    }
}

// ---------------------------------------------------------------------------
// fused_layer (swapped, 8-wave, node order, bf16 residual stream):
// GEMM1(Dm^T @ agg^T)+LN+relu -> GEMM2(W2 @ h^T)+res+LN ->
// [GEMM3(Sn^T @ x'^T) unless LAST].
// FIRST: residual = x0[rw] fp32.  !FIRST: residual = xpIn[rw] bf16.
// non-LAST stores x' bf16 (Pl/Ph words) to xpOut[rw]; LAST adds x0[rw] and
// writes final fp32 out[rw].
// ---------------------------------------------------------------------------

template <bool LAST, bool FIRST>
__global__ __launch_bounds__(512, 4) void fused_layer(
    const unsigned short* __restrict__ agg, const unsigned short* __restrict__ DmAll,
    const unsigned short* __restrict__ W2b, const unsigned short* __restrict__ SnAll,
    const int* __restrict__ blist, const int* __restrict__ boff,
    const int* __restrict__ tileOff, const float* __restrict__ dnorm,
    const float* __restrict__ b1v, const float* __restrict__ g1v,
    const float* __restrict__ e1v, const float* __restrict__ b2v,
    const float* __restrict__ g2v, const float* __restrict__ e2v,
    const float* __restrict__ rs_ptr, const float* __restrict__ x0n,
    const unsigned short* __restrict__ xpIn, unsigned short* __restrict__ xpOut,
    float* __restrict__ OutF, unsigned short* __restrict__ OutXt) {
    __shared__ unsigned short sB[128 * 128];  // 32 KiB (Dm -> W2 -> Sn)

    int tid = threadIdx.x, b = blockIdx.x;
    if (b >= tileOff[P_]) return;
    int pp = 0;
    while (pp < P_ - 1 && b >= tileOff[pp + 1]) ++pp;
    int tb = b - tileOff[pp];
    int cnt = boff[pp + 1] - boff[pp];
    int nrows = min(TM, cnt - tb * TM);
    int rowbase = boff[pp] + tb * TM;

    int lane = tid & 63, wave = tid >> 6;
    int n = lane & 15, q = lane >> 4;
    int rr = wave * 16 + n;
    int rw = (rr < nrows) ? blist[rowbase + rr] : -1;
    size_t grow = (rw >= 0) ? (size_t)rw : (size_t)N_;
    int s0 = n + ((q & 1) << 5), s1 = s0 + 16;  // exchange partners (q-group)
    bool hi = q >= 2;

    stage_B_async(DmAll + (size_t)pp * (D_ * D_), sB, wave, lane);
    bf16x8 bg[4];
#pragma unroll
    for (int kc = 0; kc < 4; ++kc)
        bg[kc] = *(const bf16x8*)(agg + grow * 128 + kc * 32 + q * 8);
    float dn = (rw >= 0) ? dnorm[rw] : 1.f;
    __syncthreads();  // #1: sB(Dm) + bg ready

    // ---- GEMM1: out1^T = Dm^T @ agg^T  (lane holds row rw, d=16t+4q+r) ----
    f32x4 acc[8];
#pragma unroll
    for (int t = 0; t < 8; ++t) acc[t] = (f32x4){0.f, 0.f, 0.f, 0.f};
#pragma unroll
    for (int kc = 0; kc < 4; ++kc) {
#pragma unroll
        for (int t = 0; t < 8; ++t) {
            int cs = ((((kc << 2) + q) ^ n) << 3);
            bf16x8 af = *(const bf16x8*)(sB + (t * 16 + n) * 128 + cs);
            acc[t] = __builtin_amdgcn_mfma_f32_16x16x32_bf16(af, bg[kc], acc[t], 0, 0, 0);
        }
    }

    // ---- LN1 + relu -> h (packed bf16 pairs Pl/Ph) ----
    unsigned Pl[8], Ph[8];
    {
        float rs1 = 0.f, rs2 = 0.f;
#pragma unroll
        for (int t = 0; t < 8; ++t) {
            float4 bb = *(const float4*)(b1v + t * 16 + q * 4);
#pragma unroll
            for (int r = 0; r < 4; ++r) {
                float v = dn * acc[t][r] + (&bb.x)[r];
                acc[t][r] = v;
                rs1 += v;
                rs2 += v * v;
            }
        }
        rs1 += __shfl_xor(rs1, 16, 64);
        rs1 += __shfl_xor(rs1, 32, 64);
        rs2 += __shfl_xor(rs2, 16, 64);
        rs2 += __shfl_xor(rs2, 32, 64);
        float mm = rs1 * (1.f / 128.f);
        float rv = rsqrtf(rs2 * (1.f / 128.f) - mm * mm + EPS_);
#pragma unroll
        for (int t = 0; t < 8; ++t) {
            float4 gg = *(const float4*)(g1v + t * 16 + q * 4);
            float4 ee = *(const float4*)(e1v + t * 16 + q * 4);
            float h0 = fmaxf((acc[t][0] - mm) * rv * gg.x + ee.x, 0.f);
            float h1 = fmaxf((acc[t][1] - mm) * rv * gg.y + ee.y, 0.f);
            float h2 = fmaxf((acc[t][2] - mm) * rv * gg.z + ee.z, 0.f);
            float h3 = fmaxf((acc[t][3] - mm) * rv * gg.w + ee.w, 0.f);
            Pl[t] = pack2bf(h0, h1);
            Ph[t] = pack2bf(h2, h3);
        }
    }

    __syncthreads();                     // #2: sB(Dm) free
    stage_B_async(W2b, sB, wave, lane);  // async; overlapped by exchange
    bf16x8 h2[4];
#pragma unroll
    for (int kc = 0; kc < 4; ++kc) XCH_FRAG(h2[kc], Pl, Ph, kc)
    __syncthreads();  // #3: sB(W2) ready

    // ---- GEMM2: out2^T = W2 @ h^T ----
#pragma unroll
    for (int t = 0; t < 8; ++t) acc[t] = (f32x4){0.f, 0.f, 0.f, 0.f};
#pragma unroll
    for (int kc = 0; kc < 4; ++kc) {
#pragma unroll
        for (int t = 0; t < 8; ++t) {
            int cs = ((((kc << 2) + q) ^ n) << 3);
            bf16x8 af = *(const bf16x8*)(sB + (t * 16 + n) * 128 + cs);
            acc[t] = __builtin_amdgcn_mfma_f32_16x16x32_bf16(af, h2[kc], acc[t], 0, 0, 0);
        }
    }

    // ---- residual (loaded at use point; TLP hides it) + LN2 -> x' ----
    float rsc = rs_ptr[0];
    {
        float xr4[8][4];
        if constexpr (FIRST) {
#pragma unroll
            for (int t = 0; t < 8; ++t) {
                if (rw >= 0) {
                    float4 v = *(const float4*)(x0n + (size_t)rw * 128 + t * 16 + q * 4);
                    xr4[t][0] = v.x; xr4[t][1] = v.y; xr4[t][2] = v.z; xr4[t][3] = v.w;
                } else {
                    xr4[t][0] = xr4[t][1] = xr4[t][2] = xr4[t][3] = 0.f;
                }
            }
        } else {
#pragma unroll
            for (int t = 0; t < 8; ++t) {
                if (rw >= 0) {
                    uint2 u = *(const uint2*)(xpIn + (size_t)rw * 128 + t * 16 + q * 4);
                    xr4[t][0] = bflo(u.x); xr4[t][1] = bfhi(u.x);
                    xr4[t][2] = bflo(u.y); xr4[t][3] = bfhi(u.y);
                } else {
                    xr4[t][0] = xr4[t][1] = xr4[t][2] = xr4[t][3] = 0.f;
                }
            }
        }
        float rs1 = 0.f, rs2 = 0.f;
#pragma unroll
        for (int t = 0; t < 8; ++t) {
            float4 bb = *(const float4*)(b2v + t * 16 + q * 4);
#pragma unroll
            for (int r = 0; r < 4; ++r) {
                float v = rsc * (acc[t][r] + (&bb.x)[r]) + xr4[t][r];
                acc[t][r] = v;
                rs1 += v;
                rs2 += v * v;
            }
        }
        rs1 += __shfl_xor(rs1, 16, 64);
        rs1 += __shfl_xor(rs1, 32, 64);
        rs2 += __shfl_xor(rs2, 16, 64);
        rs2 += __shfl_xor(rs2, 32, 64);
        float mm = rs1 * (1.f / 128.f);
        float rv = rsqrtf(rs2 * (1.f / 128.f) - mm * mm + EPS_);
        if constexpr (LAST) {
#pragma unroll
            for (int t = 0; t < 8; ++t) {
                float4 gg = *(const float4*)(g2v + t * 16 + q * 4);
                float4 ee = *(const float4*)(e2v + t * 16 + q * 4);
                if (rw >= 0) {
                    float4 xa = *(const float4*)(x0n + (size_t)rw * 128 + t * 16 + q * 4);
                    float4 o;
                    o.x = (acc[t][0] - mm) * rv * gg.x + ee.x + xa.x;
                    o.y = (acc[t][1] - mm) * rv * gg.y + ee.y + xa.y;
                    o.z = (acc[t][2] - mm) * rv * gg.z + ee.z + xa.z;
                    o.w = (acc[t][3] - mm) * rv * gg.w + ee.w + xa.w;
                    *(float4*)(OutF + (size_t)rw * 128 + t * 16 + q * 4) = o;
                }
            }
        } else {
#pragma unroll
            for (int t = 0; t < 8; ++t) {
                float4 gg = *(const float4*)(g2v + t * 16 + q * 4);
                float4 ee = *(const float4*)(e2v + t * 16 + q * 4);
                float o0 = (acc[t][0] - mm) * rv * gg.x + ee.x;
                float o1 = (acc[t][1] - mm) * rv * gg.y + ee.y;
                float o2 = (acc[t][2] - mm) * rv * gg.z + ee.z;
                float o3 = (acc[t][3] - mm) * rv * gg.w + ee.w;
                Pl[t] = pack2bf(o0, o1);
                Ph[t] = pack2bf(o2, o3);
            }
        }
    }

    if constexpr (!LAST) {
        __syncthreads();  // #4: sB(W2) free
        stage_B_async(SnAll + (size_t)pp * (D_ * D_), sB, wave, lane);
        bf16x8 x2[4];
#pragma unroll
        for (int kc = 0; kc < 4; ++kc) XCH_FRAG(x2[kc], Pl, Ph, kc)
        __syncthreads();  // #5: sB(Sn) ready

        // ---- GEMM3: xt^T = Sn^T @ x'^T ----
#pragma unroll
        for (int t = 0; t < 8; ++t) acc[t] = (f32x4){0.f, 0.f, 0.f, 0.f};
#pragma unroll
        for (int kc = 0; kc < 4; ++kc) {
#pragma unroll
            for (int t = 0; t < 8; ++t) {
                int cs = ((((kc << 2) + q) ^ n) << 3);
                bf16x8 af = *(const bf16x8*)(sB + (t * 16 + n) * 128 + cs);
                acc[t] = __builtin_amdgcn_mfma_f32_16x16x32_bf16(af, x2[kc], acc[t], 0, 0, 0);
            }
        }
        if (rw >= 0) {
#pragma unroll
            for (int t = 0; t < 8; ++t) {
                uint2 o;
                o.x = pack2bf(acc[t][0], acc[t][1]);
                o.y = pack2bf(acc[t][2], acc[t][3]);
                *(uint2*)(OutXt + (size_t)rw * 128 + t * 16 + q * 4) = o;
            }
            // bf16 x' residual store — Pl/Ph already packed (12.8MB vs 25.6MB)
#pragma unroll
            for (int t = 0; t < 8; ++t) {
                uint2 h;
                h.x = Pl[t];
                h.y = Ph[t];
                *(uint2*)(xpOut + (size_t)rw * 128 + t * 16 + q * 4) = h;
            }
        }
    }
}

// ---------------------------------------------------------------------------
// Host launch
// ---------------------------------------------------------------------------

extern "C" void kernel_launch(void* const* d_in, const int* in_sizes, int n_in,
                              void* d_out, int out_size, void* d_ws, size_t ws_size,
                              hipStream_t stream) {
    const float* x0 = (const float*)d_in[0];
    const int* ei = (const int*)d_in[1];
    const int* ring = (const int*)d_in[2];
    const float* Wr = (const float*)d_in[3];
    const float* S = (const float*)d_in[4];
    const float* dS = (const float*)d_in[5];
    const float* R = (const float*)d_in[6];
    const float* dR = (const float*)d_in[7];
    const float* rsc = (const float*)d_in[8];
    const float* W1 = (const float*)d_in[9];
    const float* b1 = (const float*)d_in[10];
    const float* lng = (const float*)d_in[11];
    const float* lnb = (const float*)d_in[12];
    const float* W2 = (const float*)d_in[13];
    const float* b2 = (const float*)d_in[14];
    const float* ng = (const float*)d_in[15];
    const float* nb = (const float*)d_in[16];
    float* out = (float*)d_out;

    char* w = (char*)d_ws;
    auto alloc = [&](size_t bytes) {
        char* p = w;
        w += (bytes + 15) & ~(size_t)15;
        return p;
    };
    unsigned short* xb = (unsigned short*)alloc((size_t)(N_ + 1) * D_ * 2);    // bf16 x0 (+zero row)
    unsigned short* bufAb = (unsigned short*)alloc((size_t)(N_ + 1) * D_ * 2); // xt (+zero row)
    unsigned short* bufBb = (unsigned short*)alloc((size_t)(N_ + 1) * D_ * 2); // agg (+zero row)
    unsigned short* xpb = (unsigned short*)alloc((size_t)(N_ + 1) * D_ * 2);   // bf16 x' residual
    unsigned short* Sb = (unsigned short*)alloc((size_t)L_ * P_ * D_ * D_ * 2);
    unsigned short* Dmb = (unsigned short*)alloc((size_t)L_ * P_ * D_ * D_ * 2);
    unsigned short* W2b = (unsigned short*)alloc((size_t)L_ * D_ * D_ * 2);
    unsigned short* Arh = (unsigned short*)alloc((size_t)MAT * 16384 * 2);
    unsigned short* Arl = (unsigned short*)alloc((size_t)MAT * 16384 * 2);
    unsigned short* W1h = (unsigned short*)alloc((size_t)3 * 16384 * 2);
    unsigned short* W1l = (unsigned short*)alloc((size_t)3 * 16384 * 2);
    unsigned short* Wrth = (unsigned short*)alloc((size_t)3 * 16384 * 2);
    unsigned short* Wrtl = (unsigned short*)alloc((size_t)3 * 16384 * 2);
    unsigned short* T1th = (unsigned short*)alloc((size_t)MAT * 16384 * 2);
    unsigned short* T1tl = (unsigned short*)alloc((size_t)MAT * 16384 * 2);
    float* dnorm = (float*)alloc((size_t)N_ * 4);
    int* histG = (int*)alloc((size_t)HTOT * 4);
    unsigned* bufT = (unsigned*)alloc((size_t)E_ * 4);
    unsigned char* bufS8 = (unsigned char*)alloc((size_t)E_);
    unsigned short* eSrc = (unsigned short*)alloc((size_t)E_ * 2);
    int* offT = (int*)alloc((size_t)(N_ + 1) * 4);
    int* pol = (int*)alloc((size_t)N_ * 4);
    int* boff = (int*)alloc((size_t)(P_ + 1) * 4);
    int* tileOff = (int*)alloc((size_t)(P_ + 1) * 4);
    int* blist = (int*)alloc((size_t)N_ * 4);
    int* blkSum = (int*)alloc((size_t)NSB * 4);
    int* bcnt = (int*)alloc((size_t)2 * P_ * 4);  // zeroed region: bcnt + bcur
    int* bcur = bcnt + P_;

    hipMemsetAsync(bcnt, 0, (size_t)2 * P_ * 4, stream);

    const int BTILES = N_ / TM + P_;  // 399, upper bound on bucketed tiles

    setup_nk<<<NBK, 256, 0, stream>>>(ring, pol, bcnt, ei, histG);
    scanH1<<<NSB, 1024, 0, stream>>>(histG, blkSum);
    scatterTS<<<NBK, 256, 0, stream>>>(ei, histG, blkSum, bufT, bufS8);
    finprep<<<GFIN, 256, 0, stream>>>(
        x0, xb, bufAb, bufBb, S, dS, Sb, W2, W2b, R, dR, W1, Wr,
        Arh, Arl, W1h, W1l, Wrth, Wrtl,
        bufT, bufS8, histG, blkSum, offT, eSrc, dnorm, pol, bcnt, bcur,
        blist, boff, tileOff);
    // T1t[mat][k][i] = sum_j W1[l][k][j] * (R+dR)[mat][i][j]
    small_mfma<false, true, true><<<2 * MAT, 256, 0, stream>>>(
        W1h, W1l, Arh, Arl, T1th, T1tl);
    // Dmb[mat][k][d] = sum_i T1t[mat][k][i] * Wr^T[l][d][i]
    small_mfma<true, false, false><<<2 * MAT, 256, 0, stream>>>(
        T1th, T1tl, Wrth, Wrtl, Dmb, nullptr);

    // layer 0 send-transform: xt0 = x0 @ (S+dS)[0][pol]
    gemm_xt0<<<BTILES, 512, 0, stream>>>(xb, Sb, bufAb, blist, boff, tileOff);

    for (int l = 0; l < L_; ++l) {
        const size_t lPDD = (size_t)l * P_ * D_ * D_;
        const size_t lDD = (size_t)l * D_ * D_;
        const size_t lD = (size_t)l * D_;
        aggregate_bf<<<N_ / 4, 256, 0, stream>>>(bufAb, offT, eSrc, bufBb);
        if (l == 0) {
            fused_layer<false, true><<<BTILES, 512, 0, stream>>>(
                bufBb, Dmb + lPDD, W2b + lDD, Sb + lPDD + (size_t)P_ * D_ * D_,
                blist, boff, tileOff, dnorm,
                b1 + lD, lng + lD, lnb + lD, b2 + lD, ng + lD, nb + lD,
                rsc + l, x0, nullptr, xpb, nullptr, bufAb);
        } else if (l < L_ - 1) {
            fused_layer<false, false><<<BTILES, 512, 0, stream>>>(
                bufBb, Dmb + lPDD, W2b + lDD, Sb + lPDD + (size_t)P_ * D_ * D_,
                blist, boff, tileOff, dnorm,
                b1 + lD, lng + lD, lnb + lD, b2 + lD, ng + lD, nb + lD,
                rsc + l, nullptr, xpb, xpb, nullptr, bufAb);
        } else {
            fused_layer<true, false><<<BTILES, 512, 0, stream>>>(
                bufBb, Dmb + lPDD, W2b + lDD, nullptr,
                blist, boff, tileOff, dnorm,
                b1 + lD, lng + lD, lnb + lD, b2 + lD, ng + lD, nb + lD,
                rsc + l, x0, xpb, nullptr, out, nullptr);
        }
    }
}